// Round 1
// baseline (1277.099 us; speedup 1.0000x reference)
//
#include <hip/hip_runtime.h>

typedef unsigned short u16;
typedef __attribute__((ext_vector_type(8))) short bf16x8;
typedef __attribute__((ext_vector_type(4))) float f32x4;
typedef __attribute__((ext_vector_type(4))) u16 u16x4;
typedef __attribute__((ext_vector_type(8))) u16 u16x8;

__device__ __forceinline__ u16 f2bf(float f) {
    union { float f; unsigned u; } v; v.f = f;
    unsigned u = v.u;
    unsigned r = (u + 0x7fffu + ((u >> 16) & 1u)) >> 16;
    return (u16)r;
}
__device__ __forceinline__ float bf2f(u16 u) {
    union { unsigned u; float f; } v; v.u = ((unsigned)u) << 16;
    return v.f;
}

__device__ __forceinline__ void gload16(const u16* g, u16* l) {
    __builtin_amdgcn_global_load_lds((const __attribute__((address_space(1))) void*)g,
                                     (__attribute__((address_space(3))) void*)l, 16, 0, 0);
}

// ---------------- weight conversion ----------------
__global__ void cvt_bf16_kernel(const float* __restrict__ in, u16* __restrict__ out, int n4) {
    int i = blockIdx.x * 256 + threadIdx.x;
    if (i >= n4) return;
    f32x4 v = *(const f32x4*)(in + (size_t)i * 4);
    u16x4 o;
    o.x = f2bf(v.x); o.y = f2bf(v.y); o.z = f2bf(v.z); o.w = f2bf(v.w);
    *(u16x4*)(out + (size_t)i * 4) = o;
}

// W3 [1000,1024] f32 -> [1024,1024] bf16, zero-padded rows
__global__ void cvt_pad_w3_kernel(const float* __restrict__ in, u16* __restrict__ out) {
    int i = blockIdx.x * 256 + threadIdx.x;   // 262144 threads, 4 elems each
    int e = i * 4;
    int row = e >> 10;
    u16x4 o;
    if (row < 1000) {
        f32x4 v = *(const f32x4*)(in + e);
        o.x = f2bf(v.x); o.y = f2bf(v.y); o.z = f2bf(v.z); o.w = f2bf(v.w);
    } else {
        o.x = 0; o.y = 0; o.z = 0; o.w = 0;
    }
    *(u16x4*)(out + e) = o;
}

// ---------------- column stats (two-stage, deterministic) ----------------
__device__ __forceinline__ float ldval(const float* p) { return *p; }
__device__ __forceinline__ float ldval(const u16* p)  { return bf2f(*p); }

template <typename DT>
__global__ void col_stats_partial(const DT* __restrict__ X, int cols, int rows_per,
                                  float* __restrict__ part) {
    int col = blockIdx.x * 256 + threadIdx.x;
    long base = (long)blockIdx.y * rows_per * cols + col;
    float s = 0.f, ss = 0.f;
    for (int r = 0; r < rows_per; ++r) {
        float v = ldval(X + base + (long)r * cols);
        s += v; ss += v * v;
    }
    part[((long)blockIdx.y * cols + col) * 2 + 0] = s;
    part[((long)blockIdx.y * cols + col) * 2 + 1] = ss;
}

__global__ void col_stats_finalize(const float* __restrict__ part, int cols, int nblk,
                                   float inv_n, const float* __restrict__ g,
                                   const float* __restrict__ b, float* __restrict__ ab) {
    int col = blockIdx.x * 256 + threadIdx.x;
    float s = 0.f, ss = 0.f;
    for (int i = 0; i < nblk; ++i) {
        s  += part[((long)i * cols + col) * 2 + 0];
        ss += part[((long)i * cols + col) * 2 + 1];
    }
    float m = s * inv_n;
    float var = ss * inv_n - m * m;
    float a = g[col] * rsqrtf(var + 1e-5f);
    ab[col * 2 + 0] = a;
    ab[col * 2 + 1] = b[col] - m * a;
}

// ---------------- fused BN0-apply + per-channel MM block + STE argmax LUT ----------------
// forward: q = sign(z); v = LUT[c, argmax(q @ Hm), :]
__global__ __launch_bounds__(256) void mm_block_kernel(
    const float* __restrict__ x, const float* __restrict__ ab0,
    const float* __restrict__ S, const float* __restrict__ Tt,
    const float* __restrict__ Hm, const float* __restrict__ LUT,
    u16* __restrict__ v) {
    int t = threadIdx.x;
    int c = t & 127;
    int row = blockIdx.x * 2 + (t >> 7);
    const float* xp = x + (size_t)row * 1024 + c * 8;
    f32x4 xa = *(const f32x4*)xp;
    f32x4 xb = *(const f32x4*)(xp + 4);
    float xs[8] = {xa.x, xa.y, xa.z, xa.w, xb.x, xb.y, xb.z, xb.w};
    float h[8];
#pragma unroll
    for (int d = 0; d < 8; ++d) {
        int col = c * 8 + d;
        h[d] = xs[d] * ab0[col * 2] + ab0[col * 2 + 1];
    }
    float lg[16];
#pragma unroll
    for (int j = 0; j < 16; ++j) lg[j] = 0.f;
    const float* Sc = S + c * 120;   // [8][15]
    const float* Tc = Tt + c * 15;
    for (int k = 0; k < 15; ++k) {
        float a = 0.f;
#pragma unroll
        for (int d = 0; d < 8; ++d) a = fmaf(h[d], Sc[d * 15 + k], a);
        float z = (a - Tc[k]) - 1e-4f;
        float q = (z > 0.f) ? 1.f : ((z < 0.f) ? -1.f : 0.f);
        if (q != 0.f) {
            const float* hr = Hm + k * 16;
#pragma unroll
            for (int j = 0; j < 16; ++j) lg[j] = fmaf(q, hr[j], lg[j]);
        }
    }
    int jb = 0; float best = lg[0];
#pragma unroll
    for (int j = 1; j < 16; ++j) { if (lg[j] > best) { best = lg[j]; jb = j; } }
    const float* lut = LUT + (c * 16 + jb) * 8;
    u16x8 o;
#pragma unroll
    for (int d = 0; d < 8; ++d) o[d] = f2bf(lut[d]);
    *(u16x8*)(v + (size_t)row * 1024 + c * 8) = o;
}

// ---------------- BN apply + ReLU (optionally also f32 out), in-place capable ----------------
__global__ void bn_relu_apply(const u16* __restrict__ y, const float* __restrict__ ab,
                              int cols, int total4, float* __restrict__ out_f32,
                              u16* __restrict__ out_b16) {
    int i = blockIdx.x * 256 + threadIdx.x;
    if (i >= total4) return;
    int e = i * 4;
    int col = e % cols;
    u16x4 yv = *(const u16x4*)(y + e);
    float r0 = fmaxf(bf2f(yv.x) * ab[(col + 0) * 2] + ab[(col + 0) * 2 + 1], 0.f);
    float r1 = fmaxf(bf2f(yv.y) * ab[(col + 1) * 2] + ab[(col + 1) * 2 + 1], 0.f);
    float r2 = fmaxf(bf2f(yv.z) * ab[(col + 2) * 2] + ab[(col + 2) * 2 + 1], 0.f);
    float r3 = fmaxf(bf2f(yv.w) * ab[(col + 3) * 2] + ab[(col + 3) * 2 + 1], 0.f);
    if (out_f32) {
        f32x4 rf = {r0, r1, r2, r3};
        *(f32x4*)(out_f32 + (size_t)e) = rf;
    }
    u16x4 o;
    o.x = f2bf(r0); o.y = f2bf(r1); o.z = f2bf(r2); o.w = f2bf(r3);
    *(u16x4*)(out_b16 + (size_t)e) = o;
}

// ---------------- bf16 GEMM, A[M,K] x B[N,K]^T, m97 structure ----------------
template <bool STORE_BF16>
__global__ __launch_bounds__(256, 2) void gemm_bt(
    const u16* __restrict__ A, const u16* __restrict__ Bm, void* __restrict__ Cv,
    const float* __restrict__ bias, int M, int N, int K, int ldc, int ncol) {
    __shared__ u16 smA[128 * 32];
    __shared__ u16 smB[128 * 32];
    const int t = threadIdx.x;
    const int lane = t & 63;
    const int w = t >> 6;
    const int bm = blockIdx.x * 128;
    const int bn = blockIdx.y * 128;
    const int wm = (w >> 1) * 64;
    const int wn = (w & 1) * 64;

    f32x4 acc[4][4];
#pragma unroll
    for (int m = 0; m < 4; ++m)
#pragma unroll
        for (int n = 0; n < 4; ++n) acc[m][n] = (f32x4){0.f, 0.f, 0.f, 0.f};

    const int srow = lane >> 2;
    const int scol = (lane & 3) * 8;
    const u16* gA0 = A + (size_t)(bm + w * 16 + srow) * K + scol;
    const u16* gA1 = A + (size_t)(bm + 64 + w * 16 + srow) * K + scol;
    const u16* gB0 = Bm + (size_t)(bn + w * 16 + srow) * K + scol;
    const u16* gB1 = Bm + (size_t)(bn + 64 + w * 16 + srow) * K + scol;
    u16* lA0 = &smA[(w * 16) * 32];
    u16* lA1 = &smA[(64 + w * 16) * 32];
    u16* lB0 = &smB[(w * 16) * 32];
    u16* lB1 = &smB[(64 + w * 16) * 32];

    const int fr = lane & 15;
    const int kg = lane >> 4;

    for (int k0 = 0; k0 < K; k0 += 32) {
        __syncthreads();
        gload16(gA0 + k0, lA0);
        gload16(gA1 + k0, lA1);
        gload16(gB0 + k0, lB0);
        gload16(gB1 + k0, lB1);
        __syncthreads();
        bf16x8 af[4], bfr[4];
#pragma unroll
        for (int m = 0; m < 4; ++m)
            af[m] = *(const bf16x8*)&smA[(wm + m * 16 + fr) * 32 + kg * 8];
#pragma unroll
        for (int n = 0; n < 4; ++n)
            bfr[n] = *(const bf16x8*)&smB[(wn + n * 16 + fr) * 32 + kg * 8];
#pragma unroll
        for (int m = 0; m < 4; ++m)
#pragma unroll
            for (int n = 0; n < 4; ++n)
                acc[m][n] = __builtin_amdgcn_mfma_f32_16x16x32_bf16(af[m], bfr[n], acc[m][n], 0, 0, 0);
    }

    const int fq = lane >> 4;
#pragma unroll
    for (int m = 0; m < 4; ++m) {
#pragma unroll
        for (int n = 0; n < 4; ++n) {
            int row = bm + wm + m * 16 + fq * 4;
            int col = bn + wn + n * 16 + fr;
            if (STORE_BF16) {
                u16* C = (u16*)Cv;
#pragma unroll
                for (int j = 0; j < 4; ++j)
                    C[(size_t)(row + j) * ldc + col] = f2bf(acc[m][n][j]);
            } else {
                if (col < ncol) {
                    float* C = (float*)Cv;
                    float bv = bias ? bias[col] : 0.f;
#pragma unroll
                    for (int j = 0; j < 4; ++j)
                        C[(size_t)(row + j) * ldc + col] = acc[m][n][j] + bv;
                }
            }
        }
    }
}

// ---------------- row log-softmax, in place ----------------
__global__ void log_softmax_rows(float* __restrict__ y, int cols) {
    int row = blockIdx.x;
    float* p = y + (size_t)row * cols;
    __shared__ float red[256];
    int t = threadIdx.x;
    float m = -1e30f;
    for (int j = t; j < cols; j += 256) m = fmaxf(m, p[j]);
    red[t] = m;
    __syncthreads();
    for (int s = 128; s > 0; s >>= 1) {
        if (t < s) red[t] = fmaxf(red[t], red[t + s]);
        __syncthreads();
    }
    m = red[0];
    __syncthreads();
    float sum = 0.f;
    for (int j = t; j < cols; j += 256) sum += expf(p[j] - m);
    red[t] = sum;
    __syncthreads();
    for (int s = 128; s > 0; s >>= 1) {
        if (t < s) red[t] += red[t + s];
        __syncthreads();
    }
    float lse = m + logf(red[0]);
    for (int j = t; j < cols; j += 256) p[j] -= lse;
}

extern "C" void kernel_launch(void* const* d_in, const int* in_sizes, int n_in,
                              void* d_out, int out_size, void* d_ws, size_t ws_size,
                              hipStream_t stream) {
    const float* x   = (const float*)d_in[0];
    const float* n0g = (const float*)d_in[1];
    const float* n0b = (const float*)d_in[2];
    const float* S   = (const float*)d_in[3];
    const float* Hm  = (const float*)d_in[4];
    const float* Tt  = (const float*)d_in[5];
    const float* LUT = (const float*)d_in[6];
    const float* W1  = (const float*)d_in[7];
    const float* n1g = (const float*)d_in[9];
    const float* n1b = (const float*)d_in[10];
    const float* W2  = (const float*)d_in[11];
    const float* n2g = (const float*)d_in[13];
    const float* n2b = (const float*)d_in[14];
    const float* W3  = (const float*)d_in[15];
    const float* b3  = (const float*)d_in[16];

    const int B = 16384, IN = 1024, H1 = 2048, H2 = 1024;

    char* ws = (char*)d_ws;
    size_t off = 0;
    auto alloc = [&](size_t bytes) -> char* {
        char* p = ws + off;
        off += (bytes + 255) & ~(size_t)255;
        return p;
    };
    float* part = (float*)alloc(32 * 2048 * 2 * sizeof(float));
    float* ab0  = (float*)alloc(IN * 2 * sizeof(float));
    float* ab1  = (float*)alloc(H1 * 2 * sizeof(float));
    float* ab2  = (float*)alloc(H2 * 2 * sizeof(float));
    u16* W1b = (u16*)alloc((size_t)H1 * IN * 2);
    u16* W2b = (u16*)alloc((size_t)H2 * H1 * 2);
    u16* W3b = (u16*)alloc((size_t)1024 * 1024 * 2);
    u16* vb  = (u16*)alloc((size_t)B * IN * 2);        // later reused as y2/h2
    u16* y1b = (u16*)alloc((size_t)B * H1 * 2);        // y1, then h1 (in-place)

    float* out0 = (float*)d_out;                        // [16384,1000] log-softmax
    float* out1 = out0 + (size_t)B * 1000;              // [16384,2048] h1 (f32)

    // 1-3: weights to bf16 (W3 padded to 1024 rows)
    cvt_bf16_kernel<<<(H1 * IN / 4 + 255) / 256, 256, 0, stream>>>(W1, W1b, H1 * IN / 4);
    cvt_bf16_kernel<<<(H2 * H1 / 4 + 255) / 256, 256, 0, stream>>>(W2, W2b, H2 * H1 / 4);
    cvt_pad_w3_kernel<<<(1024 * 1024 / 4) / 256, 256, 0, stream>>>(W3, W3b);

    // 4-5: BN0 stats
    col_stats_partial<float><<<dim3(IN / 256, 32), 256, 0, stream>>>(x, IN, B / 32, part);
    col_stats_finalize<<<IN / 256, 256, 0, stream>>>(part, IN, 32, 1.f / B, n0g, n0b, ab0);

    // 6: fused BN0-apply + MM block -> v (bf16)
    mm_block_kernel<<<B / 2, 256, 0, stream>>>(x, ab0, S, Tt, Hm, LUT, vb);

    // 7: GEMM1: v[B,1024] x W1[2048,1024]^T -> y1 bf16 [B,2048]
    gemm_bt<true><<<dim3(B / 128, H1 / 128), 256, 0, stream>>>(vb, W1b, y1b, nullptr, B, H1, IN, H1, H1);

    // 8-10: BN1 stats + apply (+ReLU); h1 f32 to d_out, bf16 in-place
    col_stats_partial<u16><<<dim3(H1 / 256, 32), 256, 0, stream>>>(y1b, H1, B / 32, part);
    col_stats_finalize<<<H1 / 256, 256, 0, stream>>>(part, H1, 32, 1.f / B, n1g, n1b, ab1);
    bn_relu_apply<<<(B * H1 / 4 + 255) / 256, 256, 0, stream>>>(y1b, ab1, H1, B * H1 / 4, out1, y1b);

    // 11: GEMM2: h1[B,2048] x W2[1024,2048]^T -> y2 bf16 [B,1024] (reuse vb)
    gemm_bt<true><<<dim3(B / 128, H2 / 128), 256, 0, stream>>>(y1b, W2b, vb, nullptr, B, H2, H1, H2, H2);

    // 12-14: BN2 stats + apply (+ReLU), bf16 in-place
    col_stats_partial<u16><<<dim3(H2 / 256, 32), 256, 0, stream>>>(vb, H2, B / 32, part);
    col_stats_finalize<<<H2 / 256, 256, 0, stream>>>(part, H2, 32, 1.f / B, n2g, n2b, ab2);
    bn_relu_apply<<<(B * H2 / 4 + 255) / 256, 256, 0, stream>>>(vb, ab2, H2, B * H2 / 4, nullptr, vb);

    // 15: GEMM3: h2[B,1024] x W3pad[1024,1024]^T -> logits f32 [B,1000] + b3
    gemm_bt<false><<<dim3(B / 128, 1024 / 128), 256, 0, stream>>>(vb, W3b, out0, b3, B, 1024, H2, 1000, 1000);

    // 16: log-softmax in place
    log_softmax_rows<<<B, 256, 0, stream>>>(out0, 1000);
}

// Round 2
// 857.833 us; speedup vs baseline: 1.4888x; 1.4888x over previous
//
#include <hip/hip_runtime.h>

typedef unsigned short u16;
typedef __attribute__((ext_vector_type(8))) short bf16x8;
typedef __attribute__((ext_vector_type(4))) float f32x4;
typedef __attribute__((ext_vector_type(4))) u16 u16x4;
typedef __attribute__((ext_vector_type(8))) u16 u16x8;

__device__ __forceinline__ u16 f2bf(float f) {
    union { float f; unsigned u; } v; v.f = f;
    unsigned u = v.u;
    unsigned r = (u + 0x7fffu + ((u >> 16) & 1u)) >> 16;
    return (u16)r;
}
__device__ __forceinline__ float bf2f(u16 u) {
    union { unsigned u; float f; } v; v.u = ((unsigned)u) << 16;
    return v.f;
}

__device__ __forceinline__ void gload16(const u16* g, u16* l) {
    __builtin_amdgcn_global_load_lds((const __attribute__((address_space(1))) void*)g,
                                     (__attribute__((address_space(3))) void*)l, 16, 0, 0);
}

// ---------------- weight conversion ----------------
__global__ void cvt_bf16_kernel(const float* __restrict__ in, u16* __restrict__ out, int n4) {
    int i = blockIdx.x * 256 + threadIdx.x;
    if (i >= n4) return;
    f32x4 v = *(const f32x4*)(in + (size_t)i * 4);
    u16x4 o;
    o.x = f2bf(v.x); o.y = f2bf(v.y); o.z = f2bf(v.z); o.w = f2bf(v.w);
    *(u16x4*)(out + (size_t)i * 4) = o;
}

// W3 [1000,1024] f32 -> [1024,1024] bf16, zero-padded rows
__global__ void cvt_pad_w3_kernel(const float* __restrict__ in, u16* __restrict__ out) {
    int i = blockIdx.x * 256 + threadIdx.x;   // 262144 threads, 4 elems each
    int e = i * 4;
    int row = e >> 10;
    u16x4 o;
    if (row < 1000) {
        f32x4 v = *(const f32x4*)(in + e);
        o.x = f2bf(v.x); o.y = f2bf(v.y); o.z = f2bf(v.z); o.w = f2bf(v.w);
    } else {
        o.x = 0; o.y = 0; o.z = 0; o.w = 0;
    }
    *(u16x4*)(out + e) = o;
}

// ---------------- column stats (two-stage, deterministic) ----------------
__device__ __forceinline__ float ldval(const float* p) { return *p; }
__device__ __forceinline__ float ldval(const u16* p)  { return bf2f(*p); }

template <typename DT>
__global__ void col_stats_partial(const DT* __restrict__ X, int cols, int rows_per,
                                  float* __restrict__ part) {
    int col = blockIdx.x * 256 + threadIdx.x;
    long base = (long)blockIdx.y * rows_per * cols + col;
    float s = 0.f, ss = 0.f;
    for (int r = 0; r < rows_per; ++r) {
        float v = ldval(X + base + (long)r * cols);
        s += v; ss += v * v;
    }
    part[((long)blockIdx.y * cols + col) * 2 + 0] = s;
    part[((long)blockIdx.y * cols + col) * 2 + 1] = ss;
}

__global__ void col_stats_finalize(const float* __restrict__ part, int cols, int nblk,
                                   float inv_n, const float* __restrict__ g,
                                   const float* __restrict__ b, float* __restrict__ ab) {
    int col = blockIdx.x * 256 + threadIdx.x;
    float s = 0.f, ss = 0.f;
    for (int i = 0; i < nblk; ++i) {
        s  += part[((long)i * cols + col) * 2 + 0];
        ss += part[((long)i * cols + col) * 2 + 1];
    }
    float m = s * inv_n;
    float var = ss * inv_n - m * m;
    float a = g[col] * rsqrtf(var + 1e-5f);
    ab[col * 2 + 0] = a;
    ab[col * 2 + 1] = b[col] - m * a;
}

// ---------------- fused BN0-apply + per-channel MM block + STE argmax LUT ----------------
// forward: q = sign(z); v = LUT[c, argmax(q @ Hm), :]
// Block: 256 rows x 4 channels (channels wave-uniform; tables staged in LDS).
__global__ __launch_bounds__(256) void mm_block_kernel(
    const float* __restrict__ x, const float* __restrict__ ab0,
    const float* __restrict__ S, const float* __restrict__ Tt,
    const float* __restrict__ Hm, const float* __restrict__ LUT,
    u16* __restrict__ v) {
    __shared__ float sS[480];    // 4 channels x [8][15]
    __shared__ float sT[60];     // 4 x 15
    __shared__ float sHm[240];   // [15][16]
    __shared__ float sLUT[512];  // 4 x [16][8]
    __shared__ float sAB[64];    // 4 x 8 x {a,b}
    const int t = threadIdx.x;
    const int cb = blockIdx.y * 4;   // first channel of this block

    for (int i = t; i < 480; i += 256) sS[i] = S[cb * 120 + i];
    for (int i = t; i < 60; i += 256)  sT[i] = Tt[cb * 15 + i];
    for (int i = t; i < 240; i += 256) sHm[i] = Hm[i];
    for (int i = t; i < 512; i += 256) sLUT[i] = LUT[cb * 128 + i];
    for (int i = t; i < 64; i += 256)  sAB[i] = ab0[cb * 16 + i];
    __syncthreads();

    const int row = blockIdx.x * 256 + t;
    const float* xp = x + (size_t)row * 1024 + cb * 8;
    float xr[32];
#pragma unroll
    for (int i = 0; i < 8; ++i) {
        f32x4 v4 = *(const f32x4*)(xp + i * 4);
        xr[i * 4 + 0] = v4.x; xr[i * 4 + 1] = v4.y;
        xr[i * 4 + 2] = v4.z; xr[i * 4 + 3] = v4.w;
    }
    u16 ov[32];
#pragma unroll
    for (int ch = 0; ch < 4; ++ch) {
        float h[8];
#pragma unroll
        for (int d = 0; d < 8; ++d)
            h[d] = xr[ch * 8 + d] * sAB[ch * 16 + d * 2] + sAB[ch * 16 + d * 2 + 1];
        float lg[16];
#pragma unroll
        for (int j = 0; j < 16; ++j) lg[j] = 0.f;
        for (int k = 0; k < 15; ++k) {
            float a = 0.f;
#pragma unroll
            for (int d = 0; d < 8; ++d) a = fmaf(h[d], sS[ch * 120 + d * 15 + k], a);
            float z = (a - sT[ch * 15 + k]) - 1e-4f;
            float q = (z > 0.f) ? 1.f : ((z < 0.f) ? -1.f : 0.f);
#pragma unroll
            for (int j = 0; j < 16; ++j) lg[j] = fmaf(q, sHm[k * 16 + j], lg[j]);
        }
        int jb = 0; float best = lg[0];
#pragma unroll
        for (int j = 1; j < 16; ++j) { if (lg[j] > best) { best = lg[j]; jb = j; } }
#pragma unroll
        for (int d = 0; d < 8; ++d) ov[ch * 8 + d] = f2bf(sLUT[ch * 128 + jb * 8 + d]);
    }
    u16* vp = v + (size_t)row * 1024 + cb * 8;
#pragma unroll
    for (int ch = 0; ch < 4; ++ch)
        *(u16x8*)(vp + ch * 8) = *(u16x8*)&ov[ch * 8];
}

// ---------------- BN apply + ReLU (optionally also f32 out), in-place capable ----------------
__global__ void bn_relu_apply(const u16* __restrict__ y, const float* __restrict__ ab,
                              int cols, int total4, float* __restrict__ out_f32,
                              u16* __restrict__ out_b16) {
    int i = blockIdx.x * 256 + threadIdx.x;
    if (i >= total4) return;
    int e = i * 4;
    int col = e % cols;
    u16x4 yv = *(const u16x4*)(y + e);
    float r0 = fmaxf(bf2f(yv.x) * ab[(col + 0) * 2] + ab[(col + 0) * 2 + 1], 0.f);
    float r1 = fmaxf(bf2f(yv.y) * ab[(col + 1) * 2] + ab[(col + 1) * 2 + 1], 0.f);
    float r2 = fmaxf(bf2f(yv.z) * ab[(col + 2) * 2] + ab[(col + 2) * 2 + 1], 0.f);
    float r3 = fmaxf(bf2f(yv.w) * ab[(col + 3) * 2] + ab[(col + 3) * 2 + 1], 0.f);
    if (out_f32) {
        f32x4 rf = {r0, r1, r2, r3};
        *(f32x4*)(out_f32 + (size_t)e) = rf;
    }
    u16x4 o;
    o.x = f2bf(r0); o.y = f2bf(r1); o.z = f2bf(r2); o.w = f2bf(r3);
    *(u16x4*)(out_b16 + (size_t)e) = o;
}

// ---------------- bf16 GEMM, A[M,K] x B[N,K]^T, m97 structure ----------------
template <bool STORE_BF16>
__global__ __launch_bounds__(256, 2) void gemm_bt(
    const u16* __restrict__ A, const u16* __restrict__ Bm, void* __restrict__ Cv,
    const float* __restrict__ bias, int M, int N, int K, int ldc, int ncol) {
    __shared__ u16 smA[128 * 32];
    __shared__ u16 smB[128 * 32];
    const int t = threadIdx.x;
    const int lane = t & 63;
    const int w = t >> 6;
    const int bm = blockIdx.x * 128;
    const int bn = blockIdx.y * 128;
    const int wm = (w >> 1) * 64;
    const int wn = (w & 1) * 64;

    f32x4 acc[4][4];
#pragma unroll
    for (int m = 0; m < 4; ++m)
#pragma unroll
        for (int n = 0; n < 4; ++n) acc[m][n] = (f32x4){0.f, 0.f, 0.f, 0.f};

    const int srow = lane >> 2;
    const int scol = (lane & 3) * 8;
    const u16* gA0 = A + (size_t)(bm + w * 16 + srow) * K + scol;
    const u16* gA1 = A + (size_t)(bm + 64 + w * 16 + srow) * K + scol;
    const u16* gB0 = Bm + (size_t)(bn + w * 16 + srow) * K + scol;
    const u16* gB1 = Bm + (size_t)(bn + 64 + w * 16 + srow) * K + scol;
    u16* lA0 = &smA[(w * 16) * 32];
    u16* lA1 = &smA[(64 + w * 16) * 32];
    u16* lB0 = &smB[(w * 16) * 32];
    u16* lB1 = &smB[(64 + w * 16) * 32];

    const int fr = lane & 15;
    const int kg = lane >> 4;

    for (int k0 = 0; k0 < K; k0 += 32) {
        __syncthreads();
        gload16(gA0 + k0, lA0);
        gload16(gA1 + k0, lA1);
        gload16(gB0 + k0, lB0);
        gload16(gB1 + k0, lB1);
        __syncthreads();
        bf16x8 af[4], bfr[4];
#pragma unroll
        for (int m = 0; m < 4; ++m)
            af[m] = *(const bf16x8*)&smA[(wm + m * 16 + fr) * 32 + kg * 8];
#pragma unroll
        for (int n = 0; n < 4; ++n)
            bfr[n] = *(const bf16x8*)&smB[(wn + n * 16 + fr) * 32 + kg * 8];
#pragma unroll
        for (int m = 0; m < 4; ++m)
#pragma unroll
            for (int n = 0; n < 4; ++n)
                acc[m][n] = __builtin_amdgcn_mfma_f32_16x16x32_bf16(af[m], bfr[n], acc[m][n], 0, 0, 0);
    }

    const int fq = lane >> 4;
#pragma unroll
    for (int m = 0; m < 4; ++m) {
#pragma unroll
        for (int n = 0; n < 4; ++n) {
            int row = bm + wm + m * 16 + fq * 4;
            int col = bn + wn + n * 16 + fr;
            if (STORE_BF16) {
                u16* C = (u16*)Cv;
#pragma unroll
                for (int j = 0; j < 4; ++j)
                    C[(size_t)(row + j) * ldc + col] = f2bf(acc[m][n][j]);
            } else {
                if (col < ncol) {
                    float* C = (float*)Cv;
                    float bv = bias ? bias[col] : 0.f;
#pragma unroll
                    for (int j = 0; j < 4; ++j)
                        C[(size_t)(row + j) * ldc + col] = acc[m][n][j] + bv;
                }
            }
        }
    }
}

// ---------------- row log-softmax, in place ----------------
__global__ void log_softmax_rows(float* __restrict__ y, int cols) {
    int row = blockIdx.x;
    float* p = y + (size_t)row * cols;
    __shared__ float red[256];
    int t = threadIdx.x;
    float m = -1e30f;
    for (int j = t; j < cols; j += 256) m = fmaxf(m, p[j]);
    red[t] = m;
    __syncthreads();
    for (int s = 128; s > 0; s >>= 1) {
        if (t < s) red[t] = fmaxf(red[t], red[t + s]);
        __syncthreads();
    }
    m = red[0];
    __syncthreads();
    float sum = 0.f;
    for (int j = t; j < cols; j += 256) sum += expf(p[j] - m);
    red[t] = sum;
    __syncthreads();
    for (int s = 128; s > 0; s >>= 1) {
        if (t < s) red[t] += red[t + s];
        __syncthreads();
    }
    float lse = m + logf(red[0]);
    for (int j = t; j < cols; j += 256) p[j] -= lse;
}

extern "C" void kernel_launch(void* const* d_in, const int* in_sizes, int n_in,
                              void* d_out, int out_size, void* d_ws, size_t ws_size,
                              hipStream_t stream) {
    const float* x   = (const float*)d_in[0];
    const float* n0g = (const float*)d_in[1];
    const float* n0b = (const float*)d_in[2];
    const float* S   = (const float*)d_in[3];
    const float* Hm  = (const float*)d_in[4];
    const float* Tt  = (const float*)d_in[5];
    const float* LUT = (const float*)d_in[6];
    const float* W1  = (const float*)d_in[7];
    const float* n1g = (const float*)d_in[9];
    const float* n1b = (const float*)d_in[10];
    const float* W2  = (const float*)d_in[11];
    const float* n2g = (const float*)d_in[13];
    const float* n2b = (const float*)d_in[14];
    const float* W3  = (const float*)d_in[15];
    const float* b3  = (const float*)d_in[16];

    const int B = 16384, IN = 1024, H1 = 2048, H2 = 1024;

    char* ws = (char*)d_ws;
    size_t off = 0;
    auto alloc = [&](size_t bytes) -> char* {
        char* p = ws + off;
        off += (bytes + 255) & ~(size_t)255;
        return p;
    };
    float* part = (float*)alloc(32 * 2048 * 2 * sizeof(float));
    float* ab0  = (float*)alloc(IN * 2 * sizeof(float));
    float* ab1  = (float*)alloc(H1 * 2 * sizeof(float));
    float* ab2  = (float*)alloc(H2 * 2 * sizeof(float));
    u16* W1b = (u16*)alloc((size_t)H1 * IN * 2);
    u16* W2b = (u16*)alloc((size_t)H2 * H1 * 2);
    u16* W3b = (u16*)alloc((size_t)1024 * 1024 * 2);
    u16* vb  = (u16*)alloc((size_t)B * IN * 2);        // later reused as y2/h2
    u16* y1b = (u16*)alloc((size_t)B * H1 * 2);        // y1, then h1 (in-place)

    float* out0 = (float*)d_out;                        // [16384,1000] log-softmax
    float* out1 = out0 + (size_t)B * 1000;              // [16384,2048] h1 (f32)

    // 1-3: weights to bf16 (W3 padded to 1024 rows)
    cvt_bf16_kernel<<<(H1 * IN / 4 + 255) / 256, 256, 0, stream>>>(W1, W1b, H1 * IN / 4);
    cvt_bf16_kernel<<<(H2 * H1 / 4 + 255) / 256, 256, 0, stream>>>(W2, W2b, H2 * H1 / 4);
    cvt_pad_w3_kernel<<<(1024 * 1024 / 4) / 256, 256, 0, stream>>>(W3, W3b);

    // 4-5: BN0 stats
    col_stats_partial<float><<<dim3(IN / 256, 32), 256, 0, stream>>>(x, IN, B / 32, part);
    col_stats_finalize<<<IN / 256, 256, 0, stream>>>(part, IN, 32, 1.f / B, n0g, n0b, ab0);

    // 6: fused BN0-apply + MM block -> v (bf16); 256 rows x 4 channels per block
    mm_block_kernel<<<dim3(B / 256, 32), 256, 0, stream>>>(x, ab0, S, Tt, Hm, LUT, vb);

    // 7: GEMM1: v[B,1024] x W1[2048,1024]^T -> y1 bf16 [B,2048]
    gemm_bt<true><<<dim3(B / 128, H1 / 128), 256, 0, stream>>>(vb, W1b, y1b, nullptr, B, H1, IN, H1, H1);

    // 8-10: BN1 stats + apply (+ReLU); h1 f32 to d_out, bf16 in-place
    col_stats_partial<u16><<<dim3(H1 / 256, 32), 256, 0, stream>>>(y1b, H1, B / 32, part);
    col_stats_finalize<<<H1 / 256, 256, 0, stream>>>(part, H1, 32, 1.f / B, n1g, n1b, ab1);
    bn_relu_apply<<<(B * H1 / 4 + 255) / 256, 256, 0, stream>>>(y1b, ab1, H1, B * H1 / 4, out1, y1b);

    // 11: GEMM2: h1[B,2048] x W2[1024,2048]^T -> y2 bf16 [B,1024] (reuse vb)
    gemm_bt<true><<<dim3(B / 128, H2 / 128), 256, 0, stream>>>(y1b, W2b, vb, nullptr, B, H2, H1, H2, H2);

    // 12-14: BN2 stats + apply (+ReLU), bf16 in-place
    col_stats_partial<u16><<<dim3(H2 / 256, 32), 256, 0, stream>>>(vb, H2, B / 32, part);
    col_stats_finalize<<<H2 / 256, 256, 0, stream>>>(part, H2, 32, 1.f / B, n2g, n2b, ab2);
    bn_relu_apply<<<(B * H2 / 4 + 255) / 256, 256, 0, stream>>>(vb, ab2, H2, B * H2 / 4, nullptr, vb);

    // 15: GEMM3: h2[B,1024] x W3pad[1024,1024]^T -> logits f32 [B,1000] + b3
    gemm_bt<false><<<dim3(B / 128, 1024 / 128), 256, 0, stream>>>(vb, W3b, out0, b3, B, 1024, H2, 1000, 1000);

    // 16: log-softmax in place
    log_softmax_rows<<<B, 256, 0, stream>>>(out0, 1000);
}

// Round 3
// 481.613 us; speedup vs baseline: 2.6517x; 1.7812x over previous
//
#include <hip/hip_runtime.h>

typedef unsigned short u16;
typedef __attribute__((ext_vector_type(8))) short bf16x8;
typedef __attribute__((ext_vector_type(4))) float f32x4;
typedef __attribute__((ext_vector_type(4))) u16 u16x4;
typedef __attribute__((ext_vector_type(8))) u16 u16x8;

__device__ __forceinline__ u16 f2bf(float f) {
    union { float f; unsigned u; } v; v.f = f;
    unsigned u = v.u;
    unsigned r = (u + 0x7fffu + ((u >> 16) & 1u)) >> 16;
    return (u16)r;
}
__device__ __forceinline__ float bf2f(u16 u) {
    union { unsigned u; float f; } v; v.u = ((unsigned)u) << 16;
    return v.f;
}

__device__ __forceinline__ void gload16(const u16* g, u16* l) {
    __builtin_amdgcn_global_load_lds((const __attribute__((address_space(1))) void*)g,
                                     (__attribute__((address_space(3))) void*)l, 16, 0, 0);
}

// ---------------- weight conversion ----------------
__global__ void cvt_bf16_kernel(const float* __restrict__ in, u16* __restrict__ out, int n4) {
    int i = blockIdx.x * 256 + threadIdx.x;
    if (i >= n4) return;
    f32x4 v = *(const f32x4*)(in + (size_t)i * 4);
    u16x4 o;
    o.x = f2bf(v.x); o.y = f2bf(v.y); o.z = f2bf(v.z); o.w = f2bf(v.w);
    *(u16x4*)(out + (size_t)i * 4) = o;
}

// W3 [1000,1024] f32 -> [1024,1024] bf16, zero-padded rows
__global__ void cvt_pad_w3_kernel(const float* __restrict__ in, u16* __restrict__ out) {
    int i = blockIdx.x * 256 + threadIdx.x;
    int e = i * 4;
    int row = e >> 10;
    u16x4 o;
    if (row < 1000) {
        f32x4 v = *(const f32x4*)(in + e);
        o.x = f2bf(v.x); o.y = f2bf(v.y); o.z = f2bf(v.z); o.w = f2bf(v.w);
    } else {
        o.x = 0; o.y = 0; o.z = 0; o.w = 0;
    }
    *(u16x4*)(out + e) = o;
}

// ---------------- column stats (two-stage, deterministic, vectorized) ----------------
__device__ __forceinline__ f32x4 ld4(const float* p) { return *(const f32x4*)p; }
__device__ __forceinline__ f32x4 ld4(const u16* p) {
    u16x4 v = *(const u16x4*)p;
    return (f32x4){bf2f(v.x), bf2f(v.y), bf2f(v.z), bf2f(v.w)};
}

// thread owns 4 consecutive cols; blockIdx.y = row-group (of 256); 64 rows each
template <typename DT>
__global__ __launch_bounds__(256) void col_stats_partial(
    const DT* __restrict__ X, int cols, int rows_per, float* __restrict__ part) {
    int col = (blockIdx.x * 256 + threadIdx.x) * 4;
    long base = (long)blockIdx.y * rows_per * cols + col;
    f32x4 s = {0.f, 0.f, 0.f, 0.f};
    f32x4 q = {0.f, 0.f, 0.f, 0.f};
    for (int r = 0; r < rows_per; ++r) {
        f32x4 v = ld4(X + base + (long)r * cols);
        s.x += v.x; s.y += v.y; s.z += v.z; s.w += v.w;
        q.x = fmaf(v.x, v.x, q.x); q.y = fmaf(v.y, v.y, q.y);
        q.z = fmaf(v.z, v.z, q.z); q.w = fmaf(v.w, v.w, q.w);
    }
    long o = ((long)blockIdx.y * cols + col) * 2;
    f32x4 p0 = {s.x, q.x, s.y, q.y};
    f32x4 p1 = {s.z, q.z, s.w, q.w};
    *(f32x4*)(part + o) = p0;
    *(f32x4*)(part + o + 4) = p1;
}

// block: 32 cols x 8 j-groups; each group sums nblk/8 partials, LDS tree
__global__ __launch_bounds__(256) void col_stats_finalize(
    const float* __restrict__ part, int cols, int nblk, float inv_n,
    const float* __restrict__ g, const float* __restrict__ b, float* __restrict__ ab) {
    __shared__ float red[8][64];
    int cl = threadIdx.x & 31;
    int j = threadIdx.x >> 5;
    int col = blockIdx.x * 32 + cl;
    int per = nblk / 8;
    float s = 0.f, ss = 0.f;
    for (int i = 0; i < per; ++i) {
        long o = ((long)(j * per + i) * cols + col) * 2;
        s += part[o]; ss += part[o + 1];
    }
    red[j][cl * 2] = s;
    red[j][cl * 2 + 1] = ss;
    __syncthreads();
    if (threadIdx.x < 32) {
        int c = blockIdx.x * 32 + threadIdx.x;
        float fs = 0.f, fss = 0.f;
#pragma unroll
        for (int jj = 0; jj < 8; ++jj) {
            fs += red[jj][threadIdx.x * 2];
            fss += red[jj][threadIdx.x * 2 + 1];
        }
        float m = fs * inv_n;
        float var = fss * inv_n - m * m;
        float a = g[c] * rsqrtf(var + 1e-5f);
        ab[c * 2 + 0] = a;
        ab[c * 2 + 1] = b[c] - m * a;
    }
}

// ---------------- fused BN0-apply + per-channel MM block + STE argmax LUT ----------------
__global__ __launch_bounds__(256) void mm_block_kernel(
    const float* __restrict__ x, const float* __restrict__ ab0,
    const float* __restrict__ S, const float* __restrict__ Tt,
    const float* __restrict__ Hm, const float* __restrict__ LUT,
    u16* __restrict__ v) {
    __shared__ float sS[480];
    __shared__ float sT[60];
    __shared__ float sHm[240];
    __shared__ float sLUT[512];
    __shared__ float sAB[64];
    const int t = threadIdx.x;
    const int cb = blockIdx.y * 4;

    for (int i = t; i < 480; i += 256) sS[i] = S[cb * 120 + i];
    for (int i = t; i < 60; i += 256)  sT[i] = Tt[cb * 15 + i];
    for (int i = t; i < 240; i += 256) sHm[i] = Hm[i];
    for (int i = t; i < 512; i += 256) sLUT[i] = LUT[cb * 128 + i];
    for (int i = t; i < 64; i += 256)  sAB[i] = ab0[cb * 16 + i];
    __syncthreads();

    const int row = blockIdx.x * 256 + t;
    const float* xp = x + (size_t)row * 1024 + cb * 8;
    float xr[32];
#pragma unroll
    for (int i = 0; i < 8; ++i) {
        f32x4 v4 = *(const f32x4*)(xp + i * 4);
        xr[i * 4 + 0] = v4.x; xr[i * 4 + 1] = v4.y;
        xr[i * 4 + 2] = v4.z; xr[i * 4 + 3] = v4.w;
    }
    u16 ov[32];
#pragma unroll
    for (int ch = 0; ch < 4; ++ch) {
        float h[8];
#pragma unroll
        for (int d = 0; d < 8; ++d)
            h[d] = xr[ch * 8 + d] * sAB[ch * 16 + d * 2] + sAB[ch * 16 + d * 2 + 1];
        float lg[16];
#pragma unroll
        for (int j = 0; j < 16; ++j) lg[j] = 0.f;
        for (int k = 0; k < 15; ++k) {
            float a = 0.f;
#pragma unroll
            for (int d = 0; d < 8; ++d) a = fmaf(h[d], sS[ch * 120 + d * 15 + k], a);
            float z = (a - sT[ch * 15 + k]) - 1e-4f;
            float q = (z > 0.f) ? 1.f : ((z < 0.f) ? -1.f : 0.f);
#pragma unroll
            for (int j = 0; j < 16; ++j) lg[j] = fmaf(q, sHm[k * 16 + j], lg[j]);
        }
        int jb = 0; float best = lg[0];
#pragma unroll
        for (int j = 1; j < 16; ++j) { if (lg[j] > best) { best = lg[j]; jb = j; } }
#pragma unroll
        for (int d = 0; d < 8; ++d) ov[ch * 8 + d] = f2bf(sLUT[ch * 128 + jb * 8 + d]);
    }
    u16* vp = v + (size_t)row * 1024 + cb * 8;
#pragma unroll
    for (int ch = 0; ch < 4; ++ch)
        *(u16x8*)(vp + ch * 8) = *(u16x8*)&ov[ch * 8];
}

// ---------------- BN apply + ReLU ----------------
__global__ void bn_relu_apply(const u16* __restrict__ y, const float* __restrict__ ab,
                              int cols, int total4, float* __restrict__ out_f32,
                              u16* __restrict__ out_b16) {
    int i = blockIdx.x * 256 + threadIdx.x;
    if (i >= total4) return;
    int e = i * 4;
    int col = e % cols;
    u16x4 yv = *(const u16x4*)(y + e);
    float r0 = fmaxf(bf2f(yv.x) * ab[(col + 0) * 2] + ab[(col + 0) * 2 + 1], 0.f);
    float r1 = fmaxf(bf2f(yv.y) * ab[(col + 1) * 2] + ab[(col + 1) * 2 + 1], 0.f);
    float r2 = fmaxf(bf2f(yv.z) * ab[(col + 2) * 2] + ab[(col + 2) * 2 + 1], 0.f);
    float r3 = fmaxf(bf2f(yv.w) * ab[(col + 3) * 2] + ab[(col + 3) * 2 + 1], 0.f);
    if (out_f32) {
        f32x4 rf = {r0, r1, r2, r3};
        *(f32x4*)(out_f32 + (size_t)e) = rf;
    }
    u16x4 o;
    o.x = f2bf(r0); o.y = f2bf(r1); o.z = f2bf(r2); o.w = f2bf(r3);
    *(u16x4*)(out_b16 + (size_t)e) = o;
}

// ---------------- bf16 GEMM, A[M,K] x B[N,K]^T, m97 structure ----------------
template <bool STORE_BF16>
__global__ __launch_bounds__(256, 2) void gemm_bt(
    const u16* __restrict__ A, const u16* __restrict__ Bm, void* __restrict__ Cv,
    const float* __restrict__ bias, int M, int N, int K, int ldc, int ncol) {
    __shared__ u16 smA[128 * 32];
    __shared__ u16 smB[128 * 32];
    const int t = threadIdx.x;
    const int lane = t & 63;
    const int w = t >> 6;
    const int bm = blockIdx.x * 128;
    const int bn = blockIdx.y * 128;
    const int wm = (w >> 1) * 64;
    const int wn = (w & 1) * 64;

    f32x4 acc[4][4];
#pragma unroll
    for (int m = 0; m < 4; ++m)
#pragma unroll
        for (int n = 0; n < 4; ++n) acc[m][n] = (f32x4){0.f, 0.f, 0.f, 0.f};

    const int srow = lane >> 2;
    const int scol = (lane & 3) * 8;
    const u16* gA0 = A + (size_t)(bm + w * 16 + srow) * K + scol;
    const u16* gA1 = A + (size_t)(bm + 64 + w * 16 + srow) * K + scol;
    const u16* gB0 = Bm + (size_t)(bn + w * 16 + srow) * K + scol;
    const u16* gB1 = Bm + (size_t)(bn + 64 + w * 16 + srow) * K + scol;
    u16* lA0 = &smA[(w * 16) * 32];
    u16* lA1 = &smA[(64 + w * 16) * 32];
    u16* lB0 = &smB[(w * 16) * 32];
    u16* lB1 = &smB[(64 + w * 16) * 32];

    const int fr = lane & 15;
    const int kg = lane >> 4;

    for (int k0 = 0; k0 < K; k0 += 32) {
        __syncthreads();
        gload16(gA0 + k0, lA0);
        gload16(gA1 + k0, lA1);
        gload16(gB0 + k0, lB0);
        gload16(gB1 + k0, lB1);
        __syncthreads();
        bf16x8 af[4], bfr[4];
#pragma unroll
        for (int m = 0; m < 4; ++m)
            af[m] = *(const bf16x8*)&smA[(wm + m * 16 + fr) * 32 + kg * 8];
#pragma unroll
        for (int n = 0; n < 4; ++n)
            bfr[n] = *(const bf16x8*)&smB[(wn + n * 16 + fr) * 32 + kg * 8];
#pragma unroll
        for (int m = 0; m < 4; ++m)
#pragma unroll
            for (int n = 0; n < 4; ++n)
                acc[m][n] = __builtin_amdgcn_mfma_f32_16x16x32_bf16(af[m], bfr[n], acc[m][n], 0, 0, 0);
    }

    const int fq = lane >> 4;
#pragma unroll
    for (int m = 0; m < 4; ++m) {
#pragma unroll
        for (int n = 0; n < 4; ++n) {
            int row = bm + wm + m * 16 + fq * 4;
            int col = bn + wn + n * 16 + fr;
            if (STORE_BF16) {
                u16* C = (u16*)Cv;
#pragma unroll
                for (int j = 0; j < 4; ++j)
                    C[(size_t)(row + j) * ldc + col] = f2bf(acc[m][n][j]);
            } else {
                if (col < ncol) {
                    float* C = (float*)Cv;
                    float bv = bias ? bias[col] : 0.f;
#pragma unroll
                    for (int j = 0; j < 4; ++j)
                        C[(size_t)(row + j) * ldc + col] = acc[m][n][j] + bv;
                }
            }
        }
    }
}

// ---------------- row log-softmax, in place ----------------
__global__ void log_softmax_rows(float* __restrict__ y, int cols) {
    int row = blockIdx.x;
    float* p = y + (size_t)row * cols;
    __shared__ float red[256];
    int t = threadIdx.x;
    float m = -1e30f;
    for (int j = t; j < cols; j += 256) m = fmaxf(m, p[j]);
    red[t] = m;
    __syncthreads();
    for (int s = 128; s > 0; s >>= 1) {
        if (t < s) red[t] = fmaxf(red[t], red[t + s]);
        __syncthreads();
    }
    m = red[0];
    __syncthreads();
    float sum = 0.f;
    for (int j = t; j < cols; j += 256) sum += expf(p[j] - m);
    red[t] = sum;
    __syncthreads();
    for (int s = 128; s > 0; s >>= 1) {
        if (t < s) red[t] += red[t + s];
        __syncthreads();
    }
    float lse = m + logf(red[0]);
    for (int j = t; j < cols; j += 256) p[j] -= lse;
}

extern "C" void kernel_launch(void* const* d_in, const int* in_sizes, int n_in,
                              void* d_out, int out_size, void* d_ws, size_t ws_size,
                              hipStream_t stream) {
    const float* x   = (const float*)d_in[0];
    const float* n0g = (const float*)d_in[1];
    const float* n0b = (const float*)d_in[2];
    const float* S   = (const float*)d_in[3];
    const float* Hm  = (const float*)d_in[4];
    const float* Tt  = (const float*)d_in[5];
    const float* LUT = (const float*)d_in[6];
    const float* W1  = (const float*)d_in[7];
    const float* n1g = (const float*)d_in[9];
    const float* n1b = (const float*)d_in[10];
    const float* W2  = (const float*)d_in[11];
    const float* n2g = (const float*)d_in[13];
    const float* n2b = (const float*)d_in[14];
    const float* W3  = (const float*)d_in[15];
    const float* b3  = (const float*)d_in[16];

    const int B = 16384, IN = 1024, H1 = 2048, H2 = 1024;
    const int NBY = 256;  // row-groups for stats partial

    char* ws = (char*)d_ws;
    size_t off = 0;
    auto alloc = [&](size_t bytes) -> char* {
        char* p = ws + off;
        off += (bytes + 255) & ~(size_t)255;
        return p;
    };
    float* ab0  = (float*)alloc(IN * 2 * sizeof(float));
    float* ab1  = (float*)alloc(H1 * 2 * sizeof(float));
    float* ab2  = (float*)alloc(H2 * 2 * sizeof(float));
    u16* W1b = (u16*)alloc((size_t)H1 * IN * 2);
    u16* W2b = (u16*)alloc((size_t)H2 * H1 * 2);
    u16* W3b = (u16*)alloc((size_t)1024 * 1024 * 2);
    u16* vb  = (u16*)alloc((size_t)B * IN * 2);        // later reused as y2/h2
    u16* y1b = (u16*)alloc((size_t)B * H1 * 2);        // y1, then h1 (in-place)

    // stats partials aliased onto temporally-dead buffers (max 4 MB each):
    float* part_x  = (float*)vb;    // before mm_block writes vb
    float* part_y1 = (float*)vb;    // v already consumed by GEMM1; before GEMM2 writes vb
    float* part_y2 = (float*)y1b;   // h1 already consumed by GEMM2

    float* out0 = (float*)d_out;                        // [16384,1000] log-softmax
    float* out1 = out0 + (size_t)B * 1000;              // [16384,2048] h1 (f32)

    // weights to bf16 (W3 padded to 1024 rows)
    cvt_bf16_kernel<<<(H1 * IN / 4 + 255) / 256, 256, 0, stream>>>(W1, W1b, H1 * IN / 4);
    cvt_bf16_kernel<<<(H2 * H1 / 4 + 255) / 256, 256, 0, stream>>>(W2, W2b, H2 * H1 / 4);
    cvt_pad_w3_kernel<<<(1024 * 1024 / 4) / 256, 256, 0, stream>>>(W3, W3b);

    // BN0 stats on x
    col_stats_partial<float><<<dim3(IN / 1024, NBY), 256, 0, stream>>>(x, IN, B / NBY, part_x);
    col_stats_finalize<<<IN / 32, 256, 0, stream>>>(part_x, IN, NBY, 1.f / B, n0g, n0b, ab0);

    // fused BN0-apply + MM block -> v (bf16)
    mm_block_kernel<<<dim3(B / 256, 32), 256, 0, stream>>>(x, ab0, S, Tt, Hm, LUT, vb);

    // GEMM1: v[B,1024] x W1[2048,1024]^T -> y1 bf16 [B,2048]
    gemm_bt<true><<<dim3(B / 128, H1 / 128), 256, 0, stream>>>(vb, W1b, y1b, nullptr, B, H1, IN, H1, H1);

    // BN1 stats + apply (+ReLU); h1 f32 to d_out, bf16 in-place
    col_stats_partial<u16><<<dim3(H1 / 1024, NBY), 256, 0, stream>>>(y1b, H1, B / NBY, part_y1);
    col_stats_finalize<<<H1 / 32, 256, 0, stream>>>(part_y1, H1, NBY, 1.f / B, n1g, n1b, ab1);
    bn_relu_apply<<<(B * H1 / 4 + 255) / 256, 256, 0, stream>>>(y1b, ab1, H1, B * H1 / 4, out1, y1b);

    // GEMM2: h1[B,2048] x W2[1024,2048]^T -> y2 bf16 [B,1024] (reuse vb)
    gemm_bt<true><<<dim3(B / 128, H2 / 128), 256, 0, stream>>>(y1b, W2b, vb, nullptr, B, H2, H1, H2, H2);

    // BN2 stats + apply (+ReLU), bf16 in-place
    col_stats_partial<u16><<<dim3(H2 / 1024, NBY), 256, 0, stream>>>(vb, H2, B / NBY, part_y2);
    col_stats_finalize<<<H2 / 32, 256, 0, stream>>>(part_y2, H2, NBY, 1.f / B, n2g, n2b, ab2);
    bn_relu_apply<<<(B * H2 / 4 + 255) / 256, 256, 0, stream>>>(vb, ab2, H2, B * H2 / 4, nullptr, vb);

    // GEMM3: h2[B,1024] x W3pad[1024,1024]^T -> logits f32 [B,1000] + b3
    gemm_bt<false><<<dim3(B / 128, 1024 / 128), 256, 0, stream>>>(vb, W3b, out0, b3, B, 1024, H2, 1000, 1000);

    // log-softmax in place
    log_softmax_rows<<<B, 256, 0, stream>>>(out0, 1000);
}

// Round 4
// 450.565 us; speedup vs baseline: 2.8344x; 1.0689x over previous
//
#include <hip/hip_runtime.h>

typedef unsigned short u16;
typedef __attribute__((ext_vector_type(8))) short bf16x8;
typedef __attribute__((ext_vector_type(4))) float f32x4;
typedef __attribute__((ext_vector_type(4))) u16 u16x4;
typedef __attribute__((ext_vector_type(8))) u16 u16x8;

__device__ __forceinline__ u16 f2bf(float f) {
    union { float f; unsigned u; } v; v.f = f;
    unsigned u = v.u;
    unsigned r = (u + 0x7fffu + ((u >> 16) & 1u)) >> 16;
    return (u16)r;
}
__device__ __forceinline__ float bf2f(u16 u) {
    union { unsigned u; float f; } v; v.u = ((unsigned)u) << 16;
    return v.f;
}

__device__ __forceinline__ void gload16(const u16* g, u16* l) {
    __builtin_amdgcn_global_load_lds((const __attribute__((address_space(1))) void*)g,
                                     (__attribute__((address_space(3))) void*)l, 16, 0, 0);
}

// ---------------- merged weight conversion (W1, W2, W3-padded) ----------------
__device__ __forceinline__ void cvt4(const float* in, u16* out, int i) {
    f32x4 v = *(const f32x4*)(in + (size_t)i * 4);
    u16x4 o;
    o.x = f2bf(v.x); o.y = f2bf(v.y); o.z = f2bf(v.z); o.w = f2bf(v.w);
    *(u16x4*)(out + (size_t)i * 4) = o;
}

__global__ __launch_bounds__(256) void cvt_all_kernel(
    const float* __restrict__ W1, const float* __restrict__ W2, const float* __restrict__ W3,
    u16* __restrict__ W1b, u16* __restrict__ W2b, u16* __restrict__ W3b) {
    int i = blockIdx.x * 256 + threadIdx.x;
    if (i < 524288) {
        cvt4(W1, W1b, i);
    } else if (i < 1048576) {
        cvt4(W2, W2b, i - 524288);
    } else {
        int j = i - 1048576;           // < 262144, covers 1024x1024 padded W3
        int e = j * 4;
        int row = e >> 10;
        u16x4 o;
        if (row < 1000) {
            f32x4 v = *(const f32x4*)(W3 + e);
            o.x = f2bf(v.x); o.y = f2bf(v.y); o.z = f2bf(v.z); o.w = f2bf(v.w);
        } else {
            o.x = 0; o.y = 0; o.z = 0; o.w = 0;
        }
        *(u16x4*)(W3b + e) = o;
    }
}

// ---------------- BN0 column stats on x (two-stage, vectorized) ----------------
template <typename DT>
__global__ __launch_bounds__(256) void col_stats_partial(
    const DT* __restrict__ X, int cols, int rows_per, float* __restrict__ part) {
    int col = (blockIdx.x * 256 + threadIdx.x) * 4;
    long base = (long)blockIdx.y * rows_per * cols + col;
    f32x4 s = {0.f, 0.f, 0.f, 0.f};
    f32x4 q = {0.f, 0.f, 0.f, 0.f};
    for (int r = 0; r < rows_per; ++r) {
        f32x4 v = *(const f32x4*)(X + base + (long)r * cols);
        s.x += v.x; s.y += v.y; s.z += v.z; s.w += v.w;
        q.x = fmaf(v.x, v.x, q.x); q.y = fmaf(v.y, v.y, q.y);
        q.z = fmaf(v.z, v.z, q.z); q.w = fmaf(v.w, v.w, q.w);
    }
    long o = ((long)blockIdx.y * cols + col) * 2;
    f32x4 p0 = {s.x, q.x, s.y, q.y};
    f32x4 p1 = {s.z, q.z, s.w, q.w};
    *(f32x4*)(part + o) = p0;
    *(f32x4*)(part + o + 4) = p1;
}

// block: 32 cols x 8 j-groups; each group sums nblk/8 partials, LDS tree
__global__ __launch_bounds__(256) void col_stats_finalize(
    const float* __restrict__ part, int cols, int nblk, float inv_n,
    const float* __restrict__ g, const float* __restrict__ b, float* __restrict__ ab) {
    __shared__ float red[8][64];
    int cl = threadIdx.x & 31;
    int j = threadIdx.x >> 5;
    int col = blockIdx.x * 32 + cl;
    int per = nblk / 8;
    float s = 0.f, ss = 0.f;
    for (int i = 0; i < per; ++i) {
        long o = ((long)(j * per + i) * cols + col) * 2;
        s += part[o]; ss += part[o + 1];
    }
    red[j][cl * 2] = s;
    red[j][cl * 2 + 1] = ss;
    __syncthreads();
    if (threadIdx.x < 32) {
        int c = blockIdx.x * 32 + threadIdx.x;
        float fs = 0.f, fss = 0.f;
#pragma unroll
        for (int jj = 0; jj < 8; ++jj) {
            fs += red[jj][threadIdx.x * 2];
            fss += red[jj][threadIdx.x * 2 + 1];
        }
        float m = fs * inv_n;
        float var = fss * inv_n - m * m;
        float a = g[c] * rsqrtf(var + 1e-5f);
        ab[c * 2 + 0] = a;
        ab[c * 2 + 1] = b[c] - m * a;
    }
}

// ---------------- fused BN0-apply + per-channel MM block + STE argmax LUT ----------------
__global__ __launch_bounds__(256) void mm_block_kernel(
    const float* __restrict__ x, const float* __restrict__ ab0,
    const float* __restrict__ S, const float* __restrict__ Tt,
    const float* __restrict__ Hm, const float* __restrict__ LUT,
    u16* __restrict__ v) {
    __shared__ float sS[480];
    __shared__ float sT[60];
    __shared__ float sHm[240];
    __shared__ float sLUT[512];
    __shared__ float sAB[64];
    const int t = threadIdx.x;
    const int cb = blockIdx.y * 4;

    for (int i = t; i < 480; i += 256) sS[i] = S[cb * 120 + i];
    for (int i = t; i < 60; i += 256)  sT[i] = Tt[cb * 15 + i];
    for (int i = t; i < 240; i += 256) sHm[i] = Hm[i];
    for (int i = t; i < 512; i += 256) sLUT[i] = LUT[cb * 128 + i];
    for (int i = t; i < 64; i += 256)  sAB[i] = ab0[cb * 16 + i];
    __syncthreads();

    const int row = blockIdx.x * 256 + t;
    const float* xp = x + (size_t)row * 1024 + cb * 8;
    float xr[32];
#pragma unroll
    for (int i = 0; i < 8; ++i) {
        f32x4 v4 = *(const f32x4*)(xp + i * 4);
        xr[i * 4 + 0] = v4.x; xr[i * 4 + 1] = v4.y;
        xr[i * 4 + 2] = v4.z; xr[i * 4 + 3] = v4.w;
    }
    u16 ov[32];
#pragma unroll
    for (int ch = 0; ch < 4; ++ch) {
        float h[8];
#pragma unroll
        for (int d = 0; d < 8; ++d)
            h[d] = xr[ch * 8 + d] * sAB[ch * 16 + d * 2] + sAB[ch * 16 + d * 2 + 1];
        float lg[16];
#pragma unroll
        for (int j = 0; j < 16; ++j) lg[j] = 0.f;
        for (int k = 0; k < 15; ++k) {
            float a = 0.f;
#pragma unroll
            for (int d = 0; d < 8; ++d) a = fmaf(h[d], sS[ch * 120 + d * 15 + k], a);
            float z = (a - sT[ch * 15 + k]) - 1e-4f;
            float q = (z > 0.f) ? 1.f : ((z < 0.f) ? -1.f : 0.f);
#pragma unroll
            for (int j = 0; j < 16; ++j) lg[j] = fmaf(q, sHm[k * 16 + j], lg[j]);
        }
        int jb = 0; float best = lg[0];
#pragma unroll
        for (int j = 1; j < 16; ++j) { if (lg[j] > best) { best = lg[j]; jb = j; } }
#pragma unroll
        for (int d = 0; d < 8; ++d) ov[ch * 8 + d] = f2bf(sLUT[ch * 128 + jb * 8 + d]);
    }
    u16* vp = v + (size_t)row * 1024 + cb * 8;
#pragma unroll
    for (int ch = 0; ch < 4; ++ch)
        *(u16x8*)(vp + ch * 8) = *(u16x8*)&ov[ch * 8];
}

// ---------------- BN apply + ReLU (x8 vectorized) ----------------
__global__ __launch_bounds__(256) void bn_relu_apply8(
    const u16* __restrict__ y, const float* __restrict__ ab, int cols, int total8,
    float* __restrict__ out_f32, u16* __restrict__ out_b16) {
    int i = blockIdx.x * 256 + threadIdx.x;
    if (i >= total8) return;
    long e = (long)i * 8;
    int col = (int)(e % cols);
    u16x8 yv = *(const u16x8*)(y + e);
    float r[8];
#pragma unroll
    for (int d = 0; d < 8; ++d)
        r[d] = fmaxf(bf2f(yv[d]) * ab[(col + d) * 2] + ab[(col + d) * 2 + 1], 0.f);
    if (out_f32) {
        f32x4 rf0 = {r[0], r[1], r[2], r[3]};
        f32x4 rf1 = {r[4], r[5], r[6], r[7]};
        *(f32x4*)(out_f32 + e) = rf0;
        *(f32x4*)(out_f32 + e + 4) = rf1;
    }
    u16x8 o;
#pragma unroll
    for (int d = 0; d < 8; ++d) o[d] = f2bf(r[d]);
    *(u16x8*)(out_b16 + e) = o;
}

// ---------------- bf16 GEMM, A[M,K] x B[N,K]^T, m97 structure + XCD swizzle ----------------
// DO_STATS: per-column {sum, sumsq} of the block's 128x128 f32 tile -> part[M/128][N][2]
template <bool STORE_BF16, bool DO_STATS>
__global__ __launch_bounds__(256, 2) void gemm_bt(
    const u16* __restrict__ A, const u16* __restrict__ Bm, void* __restrict__ Cv,
    const float* __restrict__ bias, float* __restrict__ part,
    int M, int N, int K, int ldc, int ncol) {
    __shared__ u16 smA[128 * 32];
    __shared__ u16 smB[128 * 32];
    const int t = threadIdx.x;
    const int lane = t & 63;
    const int w = t >> 6;
    // XCD-aware bijective swizzle (all launches have nwg % 8 == 0)
    const int gx = gridDim.x;
    const int nwg = gx * gridDim.y;
    const int flat = blockIdx.y * gx + blockIdx.x;
    const int swz = (flat & 7) * (nwg >> 3) + (flat >> 3);
    const int bm = (swz % gx) * 128;
    const int bn = (swz / gx) * 128;
    const int wm = (w >> 1) * 64;
    const int wn = (w & 1) * 64;

    f32x4 acc[4][4];
#pragma unroll
    for (int m = 0; m < 4; ++m)
#pragma unroll
        for (int n = 0; n < 4; ++n) acc[m][n] = (f32x4){0.f, 0.f, 0.f, 0.f};

    const int srow = lane >> 2;
    const int scol = (lane & 3) * 8;
    const u16* gA0 = A + (size_t)(bm + w * 16 + srow) * K + scol;
    const u16* gA1 = A + (size_t)(bm + 64 + w * 16 + srow) * K + scol;
    const u16* gB0 = Bm + (size_t)(bn + w * 16 + srow) * K + scol;
    const u16* gB1 = Bm + (size_t)(bn + 64 + w * 16 + srow) * K + scol;
    u16* lA0 = &smA[(w * 16) * 32];
    u16* lA1 = &smA[(64 + w * 16) * 32];
    u16* lB0 = &smB[(w * 16) * 32];
    u16* lB1 = &smB[(64 + w * 16) * 32];

    const int fr = lane & 15;
    const int kg = lane >> 4;

    for (int k0 = 0; k0 < K; k0 += 32) {
        __syncthreads();
        gload16(gA0 + k0, lA0);
        gload16(gA1 + k0, lA1);
        gload16(gB0 + k0, lB0);
        gload16(gB1 + k0, lB1);
        __syncthreads();
        bf16x8 af[4], bfr[4];
#pragma unroll
        for (int m = 0; m < 4; ++m)
            af[m] = *(const bf16x8*)&smA[(wm + m * 16 + fr) * 32 + kg * 8];
#pragma unroll
        for (int n = 0; n < 4; ++n)
            bfr[n] = *(const bf16x8*)&smB[(wn + n * 16 + fr) * 32 + kg * 8];
#pragma unroll
        for (int m = 0; m < 4; ++m)
#pragma unroll
            for (int n = 0; n < 4; ++n)
                acc[m][n] = __builtin_amdgcn_mfma_f32_16x16x32_bf16(af[m], bfr[n], acc[m][n], 0, 0, 0);
    }

    const int fq = lane >> 4;
#pragma unroll
    for (int m = 0; m < 4; ++m) {
#pragma unroll
        for (int n = 0; n < 4; ++n) {
            int row = bm + wm + m * 16 + fq * 4;
            int col = bn + wn + n * 16 + fr;
            if (STORE_BF16) {
                u16* C = (u16*)Cv;
#pragma unroll
                for (int j = 0; j < 4; ++j)
                    C[(size_t)(row + j) * ldc + col] = f2bf(acc[m][n][j]);
            } else {
                if (col < ncol) {
                    float* C = (float*)Cv;
                    float bv = bias ? bias[col] : 0.f;
#pragma unroll
                    for (int j = 0; j < 4; ++j)
                        C[(size_t)(row + j) * ldc + col] = acc[m][n][j] + bv;
                }
            }
        }
    }

    if (DO_STATS) {
        // per-lane column partials over this block's 128 rows
        float s[4], qq[4];
#pragma unroll
        for (int n = 0; n < 4; ++n) {
            s[n] = 0.f; qq[n] = 0.f;
#pragma unroll
            for (int m = 0; m < 4; ++m)
#pragma unroll
                for (int j = 0; j < 4; ++j) {
                    float vv = acc[m][n][j];
                    s[n] += vv;
                    qq[n] = fmaf(vv, vv, qq[n]);
                }
            // reduce over the 4 fq groups (rows within the wave's 64)
            s[n] += __shfl_xor(s[n], 16); s[n] += __shfl_xor(s[n], 32);
            qq[n] += __shfl_xor(qq[n], 16); qq[n] += __shfl_xor(qq[n], 32);
        }
        __syncthreads();               // all waves done reading smA/smB
        float* smf = (float*)smA;      // reuse as [4 waves][64 cols][2]
        if (lane < 16) {
#pragma unroll
            for (int n = 0; n < 4; ++n) {
                smf[(w * 64 + n * 16 + lane) * 2 + 0] = s[n];
                smf[(w * 64 + n * 16 + lane) * 2 + 1] = qq[n];
            }
        }
        __syncthreads();
        if (t < 128) {
            int half = t >> 6, lc = t & 63;
            float S = smf[(half * 64 + lc) * 2] + smf[((half + 2) * 64 + lc) * 2];
            float Q = smf[(half * 64 + lc) * 2 + 1] + smf[((half + 2) * 64 + lc) * 2 + 1];
            long o = ((long)(bm >> 7) * N + bn + t) * 2;
            part[o] = S;
            part[o + 1] = Q;
        }
    }
}

// ---------------- row log-softmax, wave-per-row, in place ----------------
__global__ __launch_bounds__(256) void log_softmax_wave(float* __restrict__ y) {
    const int w = threadIdx.x >> 6;
    const int lane = threadIdx.x & 63;
    float* p = y + ((size_t)blockIdx.x * 4 + w) * 1000;
    float m = -1e30f;
    for (int c = lane; c < 250; c += 64) {
        f32x4 v = ((const f32x4*)p)[c];
        m = fmaxf(m, fmaxf(fmaxf(v.x, v.y), fmaxf(v.z, v.w)));
    }
#pragma unroll
    for (int d = 32; d > 0; d >>= 1) m = fmaxf(m, __shfl_xor(m, d));
    float sum = 0.f;
    for (int c = lane; c < 250; c += 64) {
        f32x4 v = ((const f32x4*)p)[c];
        sum += expf(v.x - m) + expf(v.y - m) + expf(v.z - m) + expf(v.w - m);
    }
#pragma unroll
    for (int d = 32; d > 0; d >>= 1) sum += __shfl_xor(sum, d);
    float lse = m + logf(sum);
    for (int c = lane; c < 250; c += 64) {
        f32x4 v = ((const f32x4*)p)[c];
        v.x -= lse; v.y -= lse; v.z -= lse; v.w -= lse;
        ((f32x4*)p)[c] = v;
    }
}

extern "C" void kernel_launch(void* const* d_in, const int* in_sizes, int n_in,
                              void* d_out, int out_size, void* d_ws, size_t ws_size,
                              hipStream_t stream) {
    const float* x   = (const float*)d_in[0];
    const float* n0g = (const float*)d_in[1];
    const float* n0b = (const float*)d_in[2];
    const float* S   = (const float*)d_in[3];
    const float* Hm  = (const float*)d_in[4];
    const float* Tt  = (const float*)d_in[5];
    const float* LUT = (const float*)d_in[6];
    const float* W1  = (const float*)d_in[7];
    const float* n1g = (const float*)d_in[9];
    const float* n1b = (const float*)d_in[10];
    const float* W2  = (const float*)d_in[11];
    const float* n2g = (const float*)d_in[13];
    const float* n2b = (const float*)d_in[14];
    const float* W3  = (const float*)d_in[15];
    const float* b3  = (const float*)d_in[16];

    const int B = 16384, IN = 1024, H1 = 2048, H2 = 1024;
    const int NBY0 = 512;  // BN0 partial row-groups

    char* ws = (char*)d_ws;
    size_t off = 0;
    auto alloc = [&](size_t bytes) -> char* {
        char* p = ws + off;
        off += (bytes + 255) & ~(size_t)255;
        return p;
    };
    float* ab0  = (float*)alloc(IN * 2 * sizeof(float));
    float* ab1  = (float*)alloc(H1 * 2 * sizeof(float));
    float* ab2  = (float*)alloc(H2 * 2 * sizeof(float));
    float* part0 = (float*)alloc((size_t)NBY0 * IN * 2 * sizeof(float));   // 4 MB
    float* part1 = (float*)alloc((size_t)(B / 128) * H1 * 2 * sizeof(float)); // 2 MB
    float* part2 = (float*)alloc((size_t)(B / 128) * H2 * 2 * sizeof(float)); // 1 MB
    u16* W1b = (u16*)alloc((size_t)H1 * IN * 2);
    u16* W2b = (u16*)alloc((size_t)H2 * H1 * 2);
    u16* W3b = (u16*)alloc((size_t)1024 * 1024 * 2);
    u16* vb  = (u16*)alloc((size_t)B * IN * 2);        // v, later y2/h2
    u16* y1b = (u16*)alloc((size_t)B * H1 * 2);        // y1, then h1 (in-place)

    float* out0 = (float*)d_out;                        // [16384,1000] log-softmax
    float* out1 = out0 + (size_t)B * 1000;              // [16384,2048] h1 (f32)

    // 1: all weights to bf16 (W3 padded to 1024 rows)
    cvt_all_kernel<<<5120, 256, 0, stream>>>(W1, W2, W3, W1b, W2b, W3b);

    // 2-3: BN0 stats on x
    col_stats_partial<float><<<dim3(1, NBY0), 256, 0, stream>>>(x, IN, B / NBY0, part0);
    col_stats_finalize<<<IN / 32, 256, 0, stream>>>(part0, IN, NBY0, 1.f / B, n0g, n0b, ab0);

    // 4: fused BN0-apply + MM block -> v (bf16)
    mm_block_kernel<<<dim3(B / 256, 32), 256, 0, stream>>>(x, ab0, S, Tt, Hm, LUT, vb);

    // 5: GEMM1 (+BN1 partial stats): v[B,1024] x W1^T -> y1 bf16 [B,2048]
    gemm_bt<true, true><<<dim3(B / 128, H1 / 128), 256, 0, stream>>>(
        vb, W1b, y1b, nullptr, part1, B, H1, IN, H1, H1);

    // 6-7: BN1 finalize + apply (+ReLU); h1 f32 to d_out, bf16 in-place
    col_stats_finalize<<<H1 / 32, 256, 0, stream>>>(part1, H1, B / 128, 1.f / B, n1g, n1b, ab1);
    bn_relu_apply8<<<B * H1 / 8 / 256, 256, 0, stream>>>(y1b, ab1, H1, B * H1 / 8, out1, y1b);

    // 8: GEMM2 (+BN2 partial stats): h1[B,2048] x W2^T -> y2 bf16 [B,1024] (reuse vb)
    gemm_bt<true, true><<<dim3(B / 128, H2 / 128), 256, 0, stream>>>(
        y1b, W2b, vb, nullptr, part2, B, H2, H1, H2, H2);

    // 9-10: BN2 finalize + apply (+ReLU), bf16 in-place
    col_stats_finalize<<<H2 / 32, 256, 0, stream>>>(part2, H2, B / 128, 1.f / B, n2g, n2b, ab2);
    bn_relu_apply8<<<B * H2 / 8 / 256, 256, 0, stream>>>(vb, ab2, H2, B * H2 / 8, nullptr, vb);

    // 11: GEMM3: h2[B,1024] x W3pad^T -> logits f32 [B,1000] + b3
    gemm_bt<false, false><<<dim3(B / 128, 1024 / 128), 256, 0, stream>>>(
        vb, W3b, out0, b3, nullptr, B, 1024, H2, 1000, 1000);

    // 12: log-softmax in place (wave per row)
    log_softmax_wave<<<B / 4, 256, 0, stream>>>(out0);
}

// Round 5
// 370.016 us; speedup vs baseline: 3.4515x; 1.2177x over previous
//
#include <hip/hip_runtime.h>

typedef unsigned short u16;
typedef __attribute__((ext_vector_type(8))) short bf16x8;
typedef __attribute__((ext_vector_type(4))) float f32x4;
typedef __attribute__((ext_vector_type(4))) u16 u16x4;
typedef __attribute__((ext_vector_type(8))) u16 u16x8;

__device__ __forceinline__ u16 f2bf(float f) {
    union { float f; unsigned u; } v; v.f = f;
    unsigned u = v.u;
    unsigned r = (u + 0x7fffu + ((u >> 16) & 1u)) >> 16;
    return (u16)r;
}
__device__ __forceinline__ float bf2f(u16 u) {
    union { unsigned u; float f; } v; v.u = ((unsigned)u) << 16;
    return v.f;
}

__device__ __forceinline__ void gload16(const u16* g, u16* l) {
    __builtin_amdgcn_global_load_lds((const __attribute__((address_space(1))) void*)g,
                                     (__attribute__((address_space(3))) void*)l, 16, 0, 0);
}

#define WAITV(N) asm volatile("s_waitcnt vmcnt(" #N ")" ::: "memory")

__device__ __forceinline__ void sbar() {
    __builtin_amdgcn_sched_barrier(0);
    __builtin_amdgcn_s_barrier();
    __builtin_amdgcn_sched_barrier(0);
}

// ---------------- merged weight conversion (W1, W2, W3-padded) ----------------
__device__ __forceinline__ void cvt4(const float* in, u16* out, int i) {
    f32x4 v = *(const f32x4*)(in + (size_t)i * 4);
    u16x4 o;
    o.x = f2bf(v.x); o.y = f2bf(v.y); o.z = f2bf(v.z); o.w = f2bf(v.w);
    *(u16x4*)(out + (size_t)i * 4) = o;
}

__global__ __launch_bounds__(256) void cvt_all_kernel(
    const float* __restrict__ W1, const float* __restrict__ W2, const float* __restrict__ W3,
    u16* __restrict__ W1b, u16* __restrict__ W2b, u16* __restrict__ W3b) {
    int i = blockIdx.x * 256 + threadIdx.x;
    if (i < 524288) {
        cvt4(W1, W1b, i);
    } else if (i < 1048576) {
        cvt4(W2, W2b, i - 524288);
    } else {
        int j = i - 1048576;
        int e = j * 4;
        int row = e >> 10;
        u16x4 o;
        if (row < 1000) {
            f32x4 v = *(const f32x4*)(W3 + e);
            o.x = f2bf(v.x); o.y = f2bf(v.y); o.z = f2bf(v.z); o.w = f2bf(v.w);
        } else {
            o.x = 0; o.y = 0; o.z = 0; o.w = 0;
        }
        *(u16x4*)(W3b + e) = o;
    }
}

// ---------------- BN0 column stats on x ----------------
template <typename DT>
__global__ __launch_bounds__(256) void col_stats_partial(
    const DT* __restrict__ X, int cols, int rows_per, float* __restrict__ part) {
    int col = (blockIdx.x * 256 + threadIdx.x) * 4;
    long base = (long)blockIdx.y * rows_per * cols + col;
    f32x4 s = {0.f, 0.f, 0.f, 0.f};
    f32x4 q = {0.f, 0.f, 0.f, 0.f};
    for (int r = 0; r < rows_per; ++r) {
        f32x4 v = *(const f32x4*)(X + base + (long)r * cols);
        s.x += v.x; s.y += v.y; s.z += v.z; s.w += v.w;
        q.x = fmaf(v.x, v.x, q.x); q.y = fmaf(v.y, v.y, q.y);
        q.z = fmaf(v.z, v.z, q.z); q.w = fmaf(v.w, v.w, q.w);
    }
    long o = ((long)blockIdx.y * cols + col) * 2;
    f32x4 p0 = {s.x, q.x, s.y, q.y};
    f32x4 p1 = {s.z, q.z, s.w, q.w};
    *(f32x4*)(part + o) = p0;
    *(f32x4*)(part + o + 4) = p1;
}

__global__ __launch_bounds__(256) void col_stats_finalize(
    const float* __restrict__ part, int cols, int nblk, float inv_n,
    const float* __restrict__ g, const float* __restrict__ b, float* __restrict__ ab) {
    __shared__ float red[8][64];
    int cl = threadIdx.x & 31;
    int j = threadIdx.x >> 5;
    int col = blockIdx.x * 32 + cl;
    int per = nblk / 8;
    float s = 0.f, ss = 0.f;
    for (int i = 0; i < per; ++i) {
        long o = ((long)(j * per + i) * cols + col) * 2;
        s += part[o]; ss += part[o + 1];
    }
    red[j][cl * 2] = s;
    red[j][cl * 2 + 1] = ss;
    __syncthreads();
    if (threadIdx.x < 32) {
        int c = blockIdx.x * 32 + threadIdx.x;
        float fs = 0.f, fss = 0.f;
#pragma unroll
        for (int jj = 0; jj < 8; ++jj) {
            fs += red[jj][threadIdx.x * 2];
            fss += red[jj][threadIdx.x * 2 + 1];
        }
        float m = fs * inv_n;
        float var = fss * inv_n - m * m;
        float a = g[c] * rsqrtf(var + 1e-5f);
        ab[c * 2 + 0] = a;
        ab[c * 2 + 1] = b[c] - m * a;
    }
}

// ---------------- fused BN0-apply + per-channel MM block + STE argmax LUT ----------------
__global__ __launch_bounds__(256) void mm_block_kernel(
    const float* __restrict__ x, const float* __restrict__ ab0,
    const float* __restrict__ S, const float* __restrict__ Tt,
    const float* __restrict__ Hm, const float* __restrict__ LUT,
    u16* __restrict__ v) {
    __shared__ float sS[480];
    __shared__ float sT[60];
    __shared__ float sHm[240];
    __shared__ float sLUT[512];
    __shared__ float sAB[64];
    const int t = threadIdx.x;
    const int cb = blockIdx.y * 4;

    for (int i = t; i < 480; i += 256) sS[i] = S[cb * 120 + i];
    for (int i = t; i < 60; i += 256)  sT[i] = Tt[cb * 15 + i];
    for (int i = t; i < 240; i += 256) sHm[i] = Hm[i];
    for (int i = t; i < 512; i += 256) sLUT[i] = LUT[cb * 128 + i];
    for (int i = t; i < 64; i += 256)  sAB[i] = ab0[cb * 16 + i];
    __syncthreads();

    const int row = blockIdx.x * 256 + t;
    const float* xp = x + (size_t)row * 1024 + cb * 8;
    float xr[32];
#pragma unroll
    for (int i = 0; i < 8; ++i) {
        f32x4 v4 = *(const f32x4*)(xp + i * 4);
        xr[i * 4 + 0] = v4.x; xr[i * 4 + 1] = v4.y;
        xr[i * 4 + 2] = v4.z; xr[i * 4 + 3] = v4.w;
    }
    u16 ov[32];
#pragma unroll
    for (int ch = 0; ch < 4; ++ch) {
        float h[8];
#pragma unroll
        for (int d = 0; d < 8; ++d)
            h[d] = xr[ch * 8 + d] * sAB[ch * 16 + d * 2] + sAB[ch * 16 + d * 2 + 1];
        float lg[16];
#pragma unroll
        for (int j = 0; j < 16; ++j) lg[j] = 0.f;
        for (int k = 0; k < 15; ++k) {
            float a = 0.f;
#pragma unroll
            for (int d = 0; d < 8; ++d) a = fmaf(h[d], sS[ch * 120 + d * 15 + k], a);
            float z = (a - sT[ch * 15 + k]) - 1e-4f;
            float q = (z > 0.f) ? 1.f : ((z < 0.f) ? -1.f : 0.f);
#pragma unroll
            for (int j = 0; j < 16; ++j) lg[j] = fmaf(q, sHm[k * 16 + j], lg[j]);
        }
        int jb = 0; float best = lg[0];
#pragma unroll
        for (int j = 1; j < 16; ++j) { if (lg[j] > best) { best = lg[j]; jb = j; } }
#pragma unroll
        for (int d = 0; d < 8; ++d) ov[ch * 8 + d] = f2bf(sLUT[ch * 128 + jb * 8 + d]);
    }
    u16* vp = v + (size_t)row * 1024 + cb * 8;
#pragma unroll
    for (int ch = 0; ch < 4; ++ch)
        *(u16x8*)(vp + ch * 8) = *(u16x8*)&ov[ch * 8];
}

// ---------------- BN apply + ReLU (x8 vectorized) ----------------
__global__ __launch_bounds__(256) void bn_relu_apply8(
    const u16* __restrict__ y, const float* __restrict__ ab, int cols, int total8,
    float* __restrict__ out_f32, u16* __restrict__ out_b16) {
    int i = blockIdx.x * 256 + threadIdx.x;
    if (i >= total8) return;
    long e = (long)i * 8;
    int col = (int)(e % cols);
    u16x8 yv = *(const u16x8*)(y + e);
    float r[8];
#pragma unroll
    for (int d = 0; d < 8; ++d)
        r[d] = fmaxf(bf2f(yv[d]) * ab[(col + d) * 2] + ab[(col + d) * 2 + 1], 0.f);
    if (out_f32) {
        f32x4 rf0 = {r[0], r[1], r[2], r[3]};
        f32x4 rf1 = {r[4], r[5], r[6], r[7]};
        *(f32x4*)(out_f32 + e) = rf0;
        *(f32x4*)(out_f32 + e + 4) = rf1;
    }
    u16x8 o;
#pragma unroll
    for (int d = 0; d < 8; ++d) o[d] = f2bf(r[d]);
    *(u16x8*)(out_b16 + e) = o;
}

// ---------------- 256x256 deep-pipelined bf16 GEMM, A[M,K] x B[N,K]^T ----------------
// 8 waves (2M x 4N, interleaved frags), BK=64, 2-buffer LDS (128 KiB), counted vmcnt,
// XOR-swizzled LDS (pre-swizzled global source + swizzled ds_read; rule #21).
#define MFMA16(a, b, c) __builtin_amdgcn_mfma_f32_16x16x32_bf16(a, b, c, 0, 0, 0)

template <bool STORE_BF16, bool DO_STATS>
__global__ __launch_bounds__(512, 2) void gemm256(
    const u16* __restrict__ A, const u16* __restrict__ Bm, void* __restrict__ Cv,
    const float* __restrict__ bias, float* __restrict__ part,
    int M, int N, int K, int ldc, int ncol) {
    extern __shared__ u16 lds[];
    const int BOFF = 32768;                 // u16 offset of B region (64 KiB)
    const int t = threadIdx.x, lane = t & 63, w = t >> 6;
    const int wr = w >> 2, wc = w & 3;
    const int fr = lane & 15, kg = lane >> 4;
    // XCD-aware bijective swizzle (nwg % 8 == 0 for all launches)
    const int gx = gridDim.x, nwg = gx * gridDim.y;
    const int flat = blockIdx.y * gx + blockIdx.x;
    const int swz = (flat & 7) * (nwg >> 3) + (flat >> 3);
    const int bm = (swz % gx) * 256;
    const int bn = (swz / gx) * 256;
    const int NT = K >> 6;

    // staging constants: lane covers (row8 = lane>>3, chunk = (lane&7)^row8)
    const int srow8 = lane >> 3;
    const int scc = (lane & 7) ^ srow8;
    const int L0 = w * 2;
    const u16* gAb = A + ((size_t)bm + L0 * 8 + srow8) * K + scc * 8;
    const u16* gBb = Bm + ((size_t)bn + L0 * 8 + srow8) * K + scc * 8;
    u16* ldsW = lds + L0 * 512 + lane * 8;

    // ds_read swizzle: slot = (ks*4+kg) ^ (fr&7); row low bits == fr&7 for all frags
    const int s0 = (kg ^ (fr & 7)) * 8;
    const int s1 = s0 ^ 32;
    int rA[4], rB[2];
#pragma unroll
    for (int i = 0; i < 4; ++i) rA[i] = (i * 32 + wr * 16 + fr) * 64;
#pragma unroll
    for (int p = 0; p < 2; ++p) rB[p] = (p * 64 + wc * 16 + fr) * 64;

    f32x4 acc[8][4];
#pragma unroll
    for (int m = 0; m < 8; ++m)
#pragma unroll
        for (int n = 0; n < 4; ++n) acc[m][n] = (f32x4){0.f, 0.f, 0.f, 0.f};

    bf16x8 Ar[8][2], Br[2][2];

#define STG(gp, matOff, d, half, k0)                                          \
    {                                                                         \
        u16* dst_ = ldsW + (matOff) + ((d) * 2 + (half)) * 8192;              \
        const u16* src_ = (gp) + (size_t)((half) * 128) * K + (k0);           \
        gload16(src_, dst_);                                                  \
        gload16(src_ + (size_t)8 * K, dst_ + 512);                            \
    }
#define LDF(off) (*(const bf16x8*)&lds[off])

    // prologue: stage tile 0 in order A0, B0, A1, B1  (8 loads/wave outstanding)
    STG(gAb, 0, 0, 0, 0);
    STG(gBb, BOFF, 0, 0, 0);
    STG(gAb, 0, 0, 1, 0);
    STG(gBb, BOFF, 0, 1, 0);

#pragma unroll 2
    for (int tt = 0; tt < NT - 1; ++tt) {
        const int d = tt & 1, dn = d ^ 1;
        const int k0n = (tt + 1) << 6;
        const int a0 = (d * 2) * 8192, a1 = (d * 2 + 1) * 8192;
        const int b0 = BOFF + a0, b1 = BOFF + a1;
        // ---- ph0: quad (mlo, nlo); needs A0,B0 of tile tt ----
        WAITV(4); sbar();
        STG(gAb, 0, dn, 0, k0n);
#pragma unroll
        for (int i = 0; i < 4; ++i) { Ar[i][0] = LDF(a0 + rA[i] + s0); Ar[i][1] = LDF(a0 + rA[i] + s1); }
#pragma unroll
        for (int p = 0; p < 2; ++p) { Br[p][0] = LDF(b0 + rB[p] + s0); Br[p][1] = LDF(b0 + rB[p] + s1); }
        __builtin_amdgcn_s_setprio(1);
#pragma unroll
        for (int i = 0; i < 4; ++i)
#pragma unroll
            for (int p = 0; p < 2; ++p) {
                acc[i][p] = MFMA16(Ar[i][0], Br[p][0], acc[i][p]);
                acc[i][p] = MFMA16(Ar[i][1], Br[p][1], acc[i][p]);
            }
        __builtin_amdgcn_s_setprio(0);
        // ---- ph1: quad (mhi, nlo); needs A1 ----
        WAITV(4); sbar();
        STG(gBb, BOFF, dn, 0, k0n);
#pragma unroll
        for (int i = 0; i < 4; ++i) { Ar[4 + i][0] = LDF(a1 + rA[i] + s0); Ar[4 + i][1] = LDF(a1 + rA[i] + s1); }
        __builtin_amdgcn_s_setprio(1);
#pragma unroll
        for (int i = 0; i < 4; ++i)
#pragma unroll
            for (int p = 0; p < 2; ++p) {
                acc[4 + i][p] = MFMA16(Ar[4 + i][0], Br[p][0], acc[4 + i][p]);
                acc[4 + i][p] = MFMA16(Ar[4 + i][1], Br[p][1], acc[4 + i][p]);
            }
        __builtin_amdgcn_s_setprio(0);
        // ---- ph2: quad (mhi, nhi); needs B1 ----
        WAITV(4); sbar();
        STG(gAb, 0, dn, 1, k0n);
#pragma unroll
        for (int p = 0; p < 2; ++p) { Br[p][0] = LDF(b1 + rB[p] + s0); Br[p][1] = LDF(b1 + rB[p] + s1); }
        __builtin_amdgcn_s_setprio(1);
#pragma unroll
        for (int i = 0; i < 4; ++i)
#pragma unroll
            for (int p = 0; p < 2; ++p) {
                acc[4 + i][2 + p] = MFMA16(Ar[4 + i][0], Br[p][0], acc[4 + i][2 + p]);
                acc[4 + i][2 + p] = MFMA16(Ar[4 + i][1], Br[p][1], acc[4 + i][2 + p]);
            }
        __builtin_amdgcn_s_setprio(0);
        // ---- ph3: quad (mlo, nhi); all data already resident/in regs ----
        STG(gBb, BOFF, dn, 1, k0n);
        __builtin_amdgcn_s_setprio(1);
#pragma unroll
        for (int i = 0; i < 4; ++i)
#pragma unroll
            for (int p = 0; p < 2; ++p) {
                acc[i][2 + p] = MFMA16(Ar[i][0], Br[p][0], acc[i][2 + p]);
                acc[i][2 + p] = MFMA16(Ar[i][1], Br[p][1], acc[i][2 + p]);
            }
        __builtin_amdgcn_s_setprio(0);
    }
    // ---- epilogue tile NT-1 (no staging; drain 4 -> 2 -> 0) ----
    {
        const int d = (NT - 1) & 1;
        const int a0 = (d * 2) * 8192, a1 = (d * 2 + 1) * 8192;
        const int b0 = BOFF + a0, b1 = BOFF + a1;
        WAITV(4); sbar();
#pragma unroll
        for (int i = 0; i < 4; ++i) { Ar[i][0] = LDF(a0 + rA[i] + s0); Ar[i][1] = LDF(a0 + rA[i] + s1); }
#pragma unroll
        for (int p = 0; p < 2; ++p) { Br[p][0] = LDF(b0 + rB[p] + s0); Br[p][1] = LDF(b0 + rB[p] + s1); }
        __builtin_amdgcn_s_setprio(1);
#pragma unroll
        for (int i = 0; i < 4; ++i)
#pragma unroll
            for (int p = 0; p < 2; ++p) {
                acc[i][p] = MFMA16(Ar[i][0], Br[p][0], acc[i][p]);
                acc[i][p] = MFMA16(Ar[i][1], Br[p][1], acc[i][p]);
            }
        __builtin_amdgcn_s_setprio(0);
        WAITV(2); sbar();
#pragma unroll
        for (int i = 0; i < 4; ++i) { Ar[4 + i][0] = LDF(a1 + rA[i] + s0); Ar[4 + i][1] = LDF(a1 + rA[i] + s1); }
        __builtin_amdgcn_s_setprio(1);
#pragma unroll
        for (int i = 0; i < 4; ++i)
#pragma unroll
            for (int p = 0; p < 2; ++p) {
                acc[4 + i][p] = MFMA16(Ar[4 + i][0], Br[p][0], acc[4 + i][p]);
                acc[4 + i][p] = MFMA16(Ar[4 + i][1], Br[p][1], acc[4 + i][p]);
            }
        __builtin_amdgcn_s_setprio(0);
        WAITV(0); sbar();
#pragma unroll
        for (int p = 0; p < 2; ++p) { Br[p][0] = LDF(b1 + rB[p] + s0); Br[p][1] = LDF(b1 + rB[p] + s1); }
        __builtin_amdgcn_s_setprio(1);
#pragma unroll
        for (int i = 0; i < 4; ++i)
#pragma unroll
            for (int p = 0; p < 2; ++p) {
                acc[4 + i][2 + p] = MFMA16(Ar[4 + i][0], Br[p][0], acc[4 + i][2 + p]);
                acc[4 + i][2 + p] = MFMA16(Ar[4 + i][1], Br[p][1], acc[4 + i][2 + p]);
                acc[i][2 + p] = MFMA16(Ar[i][0], Br[p][0], acc[i][2 + p]);
                acc[i][2 + p] = MFMA16(Ar[i][1], Br[p][1], acc[i][2 + p]);
            }
        __builtin_amdgcn_s_setprio(0);
    }

    // ---- C write ----
    const int fq = lane >> 4;
#pragma unroll
    for (int m = 0; m < 8; ++m) {
#pragma unroll
        for (int n = 0; n < 4; ++n) {
            int row = bm + m * 32 + wr * 16 + fq * 4;
            int col = bn + n * 64 + wc * 16 + fr;
            if (STORE_BF16) {
                u16* C = (u16*)Cv;
#pragma unroll
                for (int j = 0; j < 4; ++j)
                    C[(size_t)(row + j) * ldc + col] = f2bf(acc[m][n][j]);
            } else {
                if (col < ncol) {
                    float* C = (float*)Cv;
                    float bv = bias ? bias[col] : 0.f;
#pragma unroll
                    for (int j = 0; j < 4; ++j)
                        C[(size_t)(row + j) * ldc + col] = acc[m][n][j] + bv;
                }
            }
        }
    }

    // ---- per-column {sum, sumsq} partials for fused BN stats ----
    if (DO_STATS) {
        __syncthreads();
        float* smf = (float*)lds;   // [8 waves][64 cols][2]
        float sv[4], qv[4];
#pragma unroll
        for (int n = 0; n < 4; ++n) {
            float s = 0.f, q = 0.f;
#pragma unroll
            for (int m = 0; m < 8; ++m)
#pragma unroll
                for (int j = 0; j < 4; ++j) {
                    float vv = acc[m][n][j];
                    s += vv;
                    q = fmaf(vv, vv, q);
                }
            s += __shfl_xor(s, 16); s += __shfl_xor(s, 32);
            q += __shfl_xor(q, 16); q += __shfl_xor(q, 32);
            sv[n] = s; qv[n] = q;
        }
        if (lane < 16) {
#pragma unroll
            for (int n = 0; n < 4; ++n) {
                smf[(w * 64 + n * 16 + lane) * 2 + 0] = sv[n];
                smf[(w * 64 + n * 16 + lane) * 2 + 1] = qv[n];
            }
        }
        __syncthreads();
        if (t < 256) {
            int n = t >> 6, wcq = (t >> 4) & 3, frq = t & 15;
            int i0 = (wcq * 64 + n * 16 + frq) * 2;
            int i1 = ((4 + wcq) * 64 + n * 16 + frq) * 2;
            long o = ((long)(bm >> 8) * N + bn + t) * 2;
            part[o] = smf[i0] + smf[i1];
            part[o + 1] = smf[i0 + 1] + smf[i1 + 1];
        }
    }
#undef STG
#undef LDF
}

// ---------------- row log-softmax, wave-per-row, in place ----------------
__global__ __launch_bounds__(256) void log_softmax_wave(float* __restrict__ y) {
    const int w = threadIdx.x >> 6;
    const int lane = threadIdx.x & 63;
    float* p = y + ((size_t)blockIdx.x * 4 + w) * 1000;
    float m = -1e30f;
    for (int c = lane; c < 250; c += 64) {
        f32x4 v = ((const f32x4*)p)[c];
        m = fmaxf(m, fmaxf(fmaxf(v.x, v.y), fmaxf(v.z, v.w)));
    }
#pragma unroll
    for (int d = 32; d > 0; d >>= 1) m = fmaxf(m, __shfl_xor(m, d));
    float sum = 0.f;
    for (int c = lane; c < 250; c += 64) {
        f32x4 v = ((const f32x4*)p)[c];
        sum += expf(v.x - m) + expf(v.y - m) + expf(v.z - m) + expf(v.w - m);
    }
#pragma unroll
    for (int d = 32; d > 0; d >>= 1) sum += __shfl_xor(sum, d);
    float lse = m + logf(sum);
    for (int c = lane; c < 250; c += 64) {
        f32x4 v = ((const f32x4*)p)[c];
        v.x -= lse; v.y -= lse; v.z -= lse; v.w -= lse;
        ((f32x4*)p)[c] = v;
    }
}

extern "C" void kernel_launch(void* const* d_in, const int* in_sizes, int n_in,
                              void* d_out, int out_size, void* d_ws, size_t ws_size,
                              hipStream_t stream) {
    const float* x   = (const float*)d_in[0];
    const float* n0g = (const float*)d_in[1];
    const float* n0b = (const float*)d_in[2];
    const float* S   = (const float*)d_in[3];
    const float* Hm  = (const float*)d_in[4];
    const float* Tt  = (const float*)d_in[5];
    const float* LUT = (const float*)d_in[6];
    const float* W1  = (const float*)d_in[7];
    const float* n1g = (const float*)d_in[9];
    const float* n1b = (const float*)d_in[10];
    const float* W2  = (const float*)d_in[11];
    const float* n2g = (const float*)d_in[13];
    const float* n2b = (const float*)d_in[14];
    const float* W3  = (const float*)d_in[15];
    const float* b3  = (const float*)d_in[16];

    const int B = 16384, IN = 1024, H1 = 2048, H2 = 1024;
    const int NBY0 = 512;

    // allow 128 KiB dynamic LDS for the GEMM kernels (host-side, capture-safe)
    hipFuncSetAttribute((const void*)&gemm256<true, true>,
                        hipFuncAttributeMaxDynamicSharedMemorySize, 131072);
    hipFuncSetAttribute((const void*)&gemm256<false, false>,
                        hipFuncAttributeMaxDynamicSharedMemorySize, 131072);

    char* ws = (char*)d_ws;
    size_t off = 0;
    auto alloc = [&](size_t bytes) -> char* {
        char* p = ws + off;
        off += (bytes + 255) & ~(size_t)255;
        return p;
    };
    float* ab0  = (float*)alloc(IN * 2 * sizeof(float));
    float* ab1  = (float*)alloc(H1 * 2 * sizeof(float));
    float* ab2  = (float*)alloc(H2 * 2 * sizeof(float));
    float* part0 = (float*)alloc((size_t)NBY0 * IN * 2 * sizeof(float));
    float* part1 = (float*)alloc((size_t)(B / 256) * H1 * 2 * sizeof(float));
    float* part2 = (float*)alloc((size_t)(B / 256) * H2 * 2 * sizeof(float));
    u16* W1b = (u16*)alloc((size_t)H1 * IN * 2);
    u16* W2b = (u16*)alloc((size_t)H2 * H1 * 2);
    u16* W3b = (u16*)alloc((size_t)1024 * 1024 * 2);
    u16* vb  = (u16*)alloc((size_t)B * IN * 2);        // v, later y2/h2
    u16* y1b = (u16*)alloc((size_t)B * H1 * 2);        // y1, then h1 (in-place)

    float* out0 = (float*)d_out;                        // [16384,1000]
    float* out1 = out0 + (size_t)B * 1000;              // [16384,2048] h1 f32

    cvt_all_kernel<<<5120, 256, 0, stream>>>(W1, W2, W3, W1b, W2b, W3b);

    col_stats_partial<float><<<dim3(1, NBY0), 256, 0, stream>>>(x, IN, B / NBY0, part0);
    col_stats_finalize<<<IN / 32, 256, 0, stream>>>(part0, IN, NBY0, 1.f / B, n0g, n0b, ab0);

    mm_block_kernel<<<dim3(B / 256, 32), 256, 0, stream>>>(x, ab0, S, Tt, Hm, LUT, vb);

    // GEMM1 (+BN1 stats): v[B,1024] x W1[2048,1024]^T -> y1 bf16
    gemm256<true, true><<<dim3(B / 256, H1 / 256), 512, 131072, stream>>>(
        vb, W1b, y1b, nullptr, part1, B, H1, IN, H1, H1);
    col_stats_finalize<<<H1 / 32, 256, 0, stream>>>(part1, H1, B / 256, 1.f / B, n1g, n1b, ab1);
    bn_relu_apply8<<<B * H1 / 8 / 256, 256, 0, stream>>>(y1b, ab1, H1, B * H1 / 8, out1, y1b);

    // GEMM2 (+BN2 stats): h1[B,2048] x W2[1024,2048]^T -> y2 bf16 (reuse vb)
    gemm256<true, true><<<dim3(B / 256, H2 / 256), 512, 131072, stream>>>(
        y1b, W2b, vb, nullptr, part2, B, H2, H1, H2, H2);
    col_stats_finalize<<<H2 / 32, 256, 0, stream>>>(part2, H2, B / 256, 1.f / B, n2g, n2b, ab2);
    bn_relu_apply8<<<B * H2 / 8 / 256, 256, 0, stream>>>(vb, ab2, H2, B * H2 / 8, nullptr, vb);

    // GEMM3: h2[B,1024] x W3pad[1024,1024]^T -> logits f32 + b3
    gemm256<false, false><<<dim3(B / 256, 1024 / 256), 512, 131072, stream>>>(
        vb, W3b, out0, b3, nullptr, B, 1024, H2, 1000, 1000);

    log_softmax_wave<<<B / 4, 256, 0, stream>>>(out0);
}